// Round 7
// baseline (599.552 us; speedup 1.0000x reference)
//
#include <hip/hip_runtime.h>
#include <math.h>

#define NT 730
#define NS 2000
#define NH 16
#define NG 32
#define NR 15
#define HID 256
#define NSNH 32000

// 2*log2(e): pre-folded into BASE12/CC4 so the hidden-layer arg is a bare fma.
// tanh(x) = 1 - 2*r, r = rcp(exp2(SC*x)+1). The (1-2r) affine is folded into
// the MFMA weights (W2H = -2*w_f16) and the accumulator init
// (BIAS48 = b + sum_k w_f16), so only r is fed to the matrix core.
#define SC 2.885390081777927f
#define INV6 0.16666666666666666f

typedef _Float16 f16x8 __attribute__((ext_vector_type(8)));
typedef __fp16 fp16v2 __attribute__((ext_vector_type(2)));   // cvt_pkrtz native return type
typedef float f32x4 __attribute__((ext_vector_type(4)));

__device__ __forceinline__ float tanh_pre(float y) {   // y = SC * x
    float e = __builtin_amdgcn_exp2f(y);
    float r = __builtin_amdgcn_rcpf(e + 1.f);
    return fmaf(-2.f, r, 1.f);
}
__device__ __forceinline__ float fast_tanh(float x) { return tanh_pre(x * SC); }
__device__ __forceinline__ float sigmoidf_(float x) { return 1.f / (1.f + __expf(-x)); }

__device__ __forceinline__ float rcp_pre(float y) {    // r = 1/(1+exp2(y)); tanh = 1-2r
    float e = __builtin_amdgcn_exp2f(y);
    return __builtin_amdgcn_rcpf(e + 1.f);
}
__device__ __forceinline__ f16x8 rcp8(float4 lo, float4 hi) {
    union { fp16v2 h[4]; f16x8 v; } u;
    u.h[0] = __builtin_amdgcn_cvt_pkrtz(rcp_pre(lo.x), rcp_pre(lo.y));
    u.h[1] = __builtin_amdgcn_cvt_pkrtz(rcp_pre(lo.z), rcp_pre(lo.w));
    u.h[2] = __builtin_amdgcn_cvt_pkrtz(rcp_pre(hi.x), rcp_pre(hi.y));
    u.h[3] = __builtin_amdgcn_cvt_pkrtz(rcp_pre(hi.z), rcp_pre(hi.w));
    return u.v;
}

// ---------------------------------------------------------------------------
// k_pack: CC4[k] = (SC*a1, SC*c0, SC*c1, SC*c2) interleaved float4.
//   W2H folding: cols 0..31 x(-2/6) (hsig->clamp); cols 32..47 x(-2*SC)
//   (exp->exp2). BIAS48[j] = bias + sum_k (-0.5)*w_f16.
// ---------------------------------------------------------------------------
__global__ __launch_bounds__(256) void k_pack(
    const float* __restrict__ T1W1, const float* __restrict__ T2W1,
    const float* __restrict__ T1W2, const float* __restrict__ T2W2,
    const float* __restrict__ T1b2, const float* __restrict__ T2b2,
    float4* __restrict__ CC4, _Float16* __restrict__ W2H,
    float* __restrict__ BIAS48)
{
    int k = threadIdx.x;
    CC4[k] = make_float4(SC * T1W1[k * (1 + NG)],
                         SC * T2W1[k * (3 + NG)],
                         SC * T2W1[k * (3 + NG) + 1],
                         SC * T2W1[k * (3 + NG) + 2]);
    for (int c = 0; c < 48; ++c) {
        float w = (c < 32) ? (INV6 * T1W2[c * HID + k]) : (SC * T2W2[(c - 32) * HID + k]);
        W2H[c * HID + k] = (_Float16)(-2.f * w);
    }
    if (k < 48) {
        float s = 0.f;
        if (k < 32) {
            for (int i = 0; i < HID; ++i)
                s += -0.5f * (float)(_Float16)(-2.f * INV6 * T1W2[k * HID + i]);
            BIAS48[k] = fmaf(T1b2[k], INV6, 0.5f) + s;
        } else {
            for (int i = 0; i < HID; ++i)
                s += -0.5f * (float)(_Float16)(-2.f * SC * T2W2[(k - 32) * HID + i]);
            BIAS48[k] = SC * T2b2[k - 32] + s;
        }
    }
}

// ---------------------------------------------------------------------------
// k_basin: 4 basins per block; BASE12[s][k] = (SC*b1, SC*b2) interleaved.
// ---------------------------------------------------------------------------
__global__ __launch_bounds__(256) void k_basin(
    const float* __restrict__ XC,
    const float* __restrict__ fcW1, const float* __restrict__ fcb1,
    const float* __restrict__ fcW2, const float* __restrict__ fcb2,
    const float* __restrict__ fRW1, const float* __restrict__ fRb1,
    const float* __restrict__ fRW2, const float* __restrict__ fRb2,
    const float* __restrict__ T1W1, const float* __restrict__ T1b1,
    const float* __restrict__ T2W1, const float* __restrict__ T2b1,
    float* __restrict__ P8, float* __restrict__ RKGA,
    float2* __restrict__ BASE12)
{
    const int s0 = blockIdx.x * 4, tid = threadIdx.x;
    __shared__ float xcs[4][NG];
    __shared__ float h[4][HID], hR[4][HID];
    __shared__ float wbuf[4][10 * NH], wRbuf[4][NH * NR];
    __shared__ float gav[4][NH];

    if (tid < 128) xcs[tid >> 5][tid & 31] = XC[(s0 + (tid >> 5)) * NG + (tid & 31)];
    __syncthreads();

    {
        float ab0 = fcb1[tid], ab1 = ab0, ab2 = ab0, ab3 = ab0;
        float rb0 = fRb1[tid], rb1 = rb0, rb2 = rb0, rb3 = rb0;
        const float4* w4  = (const float4*)(fcW1 + tid * NG);
        const float4* wR4 = (const float4*)(fRW1 + tid * NG);
#pragma unroll
        for (int g = 0; g < NG / 4; ++g) {
            float4 wv = w4[g], rv = wR4[g];
            float4 x0 = *(const float4*)&xcs[0][g * 4];
            float4 x1 = *(const float4*)&xcs[1][g * 4];
            float4 x2 = *(const float4*)&xcs[2][g * 4];
            float4 x3 = *(const float4*)&xcs[3][g * 4];
            ab0 += x0.x*wv.x + x0.y*wv.y + x0.z*wv.z + x0.w*wv.w;
            ab1 += x1.x*wv.x + x1.y*wv.y + x1.z*wv.z + x1.w*wv.w;
            ab2 += x2.x*wv.x + x2.y*wv.y + x2.z*wv.z + x2.w*wv.w;
            ab3 += x3.x*wv.x + x3.y*wv.y + x3.z*wv.z + x3.w*wv.w;
            rb0 += x0.x*rv.x + x0.y*rv.y + x0.z*rv.z + x0.w*rv.w;
            rb1 += x1.x*rv.x + x1.y*rv.y + x1.z*rv.z + x1.w*rv.w;
            rb2 += x2.x*rv.x + x2.y*rv.y + x2.z*rv.z + x2.w*rv.w;
            rb3 += x3.x*rv.x + x3.y*rv.y + x3.z*rv.z + x3.w*rv.w;
        }
        h[0][tid] = fast_tanh(ab0); h[1][tid] = fast_tanh(ab1);
        h[2][tid] = fast_tanh(ab2); h[3][tid] = fast_tanh(ab3);
        hR[0][tid] = fast_tanh(rb0); hR[1][tid] = fast_tanh(rb1);
        hR[2][tid] = fast_tanh(rb2); hR[3][tid] = fast_tanh(rb3);

        float b10 = T1b1[tid], b11 = b10, b12 = b10, b13 = b10;
        float b20 = T2b1[tid], b21 = b20, b22 = b20, b23 = b20;
        const float* w1 = T1W1 + tid * (1 + NG) + 1;
        const float* w2 = T2W1 + tid * (3 + NG) + 3;
#pragma unroll 8
        for (int g = 0; g < NG; ++g) {
            float w1g = w1[g], w2g = w2[g];
            float x0 = xcs[0][g], x1 = xcs[1][g], x2 = xcs[2][g], x3 = xcs[3][g];
            b10 = fmaf(x0, w1g, b10); b11 = fmaf(x1, w1g, b11);
            b12 = fmaf(x2, w1g, b12); b13 = fmaf(x3, w1g, b13);
            b20 = fmaf(x0, w2g, b20); b21 = fmaf(x1, w2g, b21);
            b22 = fmaf(x2, w2g, b22); b23 = fmaf(x3, w2g, b23);
        }
        BASE12[(size_t)(s0 + 0) * HID + tid] = make_float2(SC * b10, SC * b20);
        BASE12[(size_t)(s0 + 1) * HID + tid] = make_float2(SC * b11, SC * b21);
        BASE12[(size_t)(s0 + 2) * HID + tid] = make_float2(SC * b12, SC * b22);
        BASE12[(size_t)(s0 + 3) * HID + tid] = make_float2(SC * b13, SC * b23);
    }
    __syncthreads();

    if (tid < 10 * NH) {
        float a0 = fcb2[tid], a1 = a0, a2 = a0, a3 = a0;
        const float4* w4 = (const float4*)(fcW2 + tid * HID);
        for (int k = 0; k < HID / 4; ++k) {
            float4 wv = w4[k];
            float4 h0 = *(const float4*)&h[0][k * 4];
            float4 h1 = *(const float4*)&h[1][k * 4];
            float4 h2 = *(const float4*)&h[2][k * 4];
            float4 h3 = *(const float4*)&h[3][k * 4];
            a0 += h0.x*wv.x + h0.y*wv.y + h0.z*wv.z + h0.w*wv.w;
            a1 += h1.x*wv.x + h1.y*wv.y + h1.z*wv.z + h1.w*wv.w;
            a2 += h2.x*wv.x + h2.y*wv.y + h2.z*wv.z + h2.w*wv.w;
            a3 += h3.x*wv.x + h3.y*wv.y + h3.z*wv.z + h3.w*wv.w;
        }
        wbuf[0][tid] = a0; wbuf[1][tid] = a1; wbuf[2][tid] = a2; wbuf[3][tid] = a3;
    }
    if (tid < NH * NR) {
        float a0 = fRb2[tid], a1 = a0, a2 = a0, a3 = a0;
        const float4* w4 = (const float4*)(fRW2 + tid * HID);
        for (int k = 0; k < HID / 4; ++k) {
            float4 wv = w4[k];
            float4 h0 = *(const float4*)&hR[0][k * 4];
            float4 h1 = *(const float4*)&hR[1][k * 4];
            float4 h2 = *(const float4*)&hR[2][k * 4];
            float4 h3 = *(const float4*)&hR[3][k * 4];
            a0 += h0.x*wv.x + h0.y*wv.y + h0.z*wv.z + h0.w*wv.w;
            a1 += h1.x*wv.x + h1.y*wv.y + h1.z*wv.z + h1.w*wv.w;
            a2 += h2.x*wv.x + h2.y*wv.y + h2.z*wv.z + h2.w*wv.w;
            a3 += h3.x*wv.x + h3.y*wv.y + h3.z*wv.z + h3.w*wv.w;
        }
        wRbuf[0][tid] = a0; wRbuf[1][tid] = a1; wRbuf[2][tid] = a2; wRbuf[3][tid] = a3;
    }
    __syncthreads();

    if (tid < 64) {
        int b = tid >> 4, hh = tid & 15;
        const float* wb = wbuf[b];
        float mx = -1e30f;
        for (int i = 0; i < NH; ++i) mx = fmaxf(mx, wb[6 * NH + i]);
        float sum = 0.f;
        for (int i = 0; i < NH; ++i) sum += expf(wb[6 * NH + i] - mx);
        gav[b][hh] = expf(wb[6 * NH + hh] - mx) / sum;

        float* p = P8 + (size_t)((s0 + b) * NH + hh) * 8;
        p[0] = sigmoidf_(wb[1 * NH + hh]);
        p[1] = sigmoidf_(wb[2 * NH + hh]);
        p[2] = sigmoidf_(wb[3 * NH + hh]);
        p[3] = sigmoidf_(wb[4 * NH + hh]) * 0.1f;
        p[4] = expf(wb[5 * NH + hh]) * 2.f;
        p[5] = fmaxf(wb[7 * NH + hh], 0.f);
        p[6] = fmaxf(wb[8 * NH + hh], 0.f);
        p[7] = fmaxf(wb[9 * NH + hh], 0.f);
    }
    __syncthreads();

    for (int it = tid; it < 4 * NH * NR; it += 256) {
        int b = it / (NH * NR), r = it % (NH * NR);
        int hh = r / NR, j = r % NR;
        RKGA[(size_t)((s0 + b) * NH + hh) * 16 + (NR - 1 - j)] =
            gav[b][hh] * fmaxf(wRbuf[b][hh * NR + j], 0.f);
    }
}

// ---------------------------------------------------------------------------
// PSE helper (vp partition).
// ---------------------------------------------------------------------------
__device__ __forceinline__ void store_pse(float4* __restrict__ PSE, long m, float2 pe, float2 t12) {
    float P = pe.x, E = pe.y, T1 = t12.x, T2 = t12.y;
    float den = T2 - T1;
    float ratio = (T1 + T2) / ((den == 0.f) ? 1.f : den);
    ratio = fminf(fmaxf(ratio, -1.f), 1.f);
    if ((T1 >= 0.f) || (T2 <= 0.f)) ratio = 0.f;
    float vp = 1.f - acosf(ratio) * (1.f / 3.1415f);
    if (T1 >= 0.f) vp = 1.f;
    if (T2 <= 0.f) vp = 0.f;
    PSE[m] = make_float4(P * (1.f - vp), P * vp, E, 0.f);
}

// ---------------------------------------------------------------------------
// k_mlp v10 (unchanged from R6 best): 2-wave/128-thread blocks, rcp fold,
//   s-fastest grid. 256us, VGPR 88, WRITE 205MB clean.
// ---------------------------------------------------------------------------
__global__ __launch_bounds__(128) void k_mlp(
    const float* __restrict__ X,
    const float2* __restrict__ BASE12, const float4* __restrict__ CC4,
    const _Float16* __restrict__ W2H, const float* __restrict__ BIAS48,
    uint2* __restrict__ VMK, float4* __restrict__ PSE)
{
    const int lane = threadIdx.x & 63;
    const int wave = threadIdx.x >> 6;
    const int quad = lane >> 4, ml = lane & 15;
    const int s0 = blockIdx.x * 16;
    const int t0 = (blockIdx.y * 2 + wave) * 4;
    const int srow = s0 + ml;

    const int tc0 = (t0 < NT) ? t0 : (NT - 1);
    const int tc1 = (t0 + 1 < NT) ? t0 + 1 : (NT - 1);
    const int tc2 = (t0 + 2 < NT) ? t0 + 2 : (NT - 1);
    const int tc3 = (t0 + 3 < NT) ? t0 + 3 : (NT - 1);

    const float* xr0 = X + ((long)tc0 * NS + srow) * 6;
    const float* xr1 = X + ((long)tc1 * NS + srow) * 6;
    const float* xr2 = X + ((long)tc2 * NS + srow) * 6;
    const float* xr3 = X + ((long)tc3 * NS + srow) * 6;
    float2 tt0 = *(const float2*)(xr0 + 2), rl0 = *(const float2*)(xr0 + 4);
    float2 tt1 = *(const float2*)(xr1 + 2), rl1 = *(const float2*)(xr1 + 4);
    float2 tt2 = *(const float2*)(xr2 + 2), rl2 = *(const float2*)(xr2 + 4);
    float2 tt3 = *(const float2*)(xr3 + 2), rl3 = *(const float2*)(xr3 + 4);

    const float bvi = BIAS48[ml];
    const float bvk = BIAS48[NH + ml];
    const float bvm = BIAS48[2 * NH + ml];
    f32x4 ac0_0 = {bvi, bvi, bvi, bvi}, ac0_1 = ac0_0, ac0_2 = ac0_0, ac0_3 = ac0_0;
    f32x4 ac1_0 = {bvk, bvk, bvk, bvk}, ac1_1 = ac1_0, ac1_2 = ac1_0, ac1_3 = ac1_0;
    f32x4 ac2_0 = {bvm, bvm, bvm, bvm}, ac2_1 = ac2_0, ac2_2 = ac2_0, ac2_3 = ac2_0;

    const float2* b12p = BASE12 + (size_t)srow * HID;
    const _Float16* wvi = W2H + (size_t)ml * HID;
    const _Float16* wvk = W2H + (size_t)(NH + ml) * HID;
    const _Float16* wvm = W2H + (size_t)(2 * NH + ml) * HID;

#pragma unroll 2
    for (int ks = 0; ks < 8; ++ks) {
        const int kb = ks * 32 + quad * 8;
        float4 cc0 = CC4[kb], cc1 = CC4[kb + 1], cc2 = CC4[kb + 2], cc3 = CC4[kb + 3];
        float4 cc4 = CC4[kb + 4], cc5 = CC4[kb + 5], cc6 = CC4[kb + 6], cc7 = CC4[kb + 7];
        float4 bA = *(const float4*)(b12p + kb);       // b1[k],b2[k],b1[k+1],b2[k+1]
        float4 bB = *(const float4*)(b12p + kb + 2);
        float4 bC = *(const float4*)(b12p + kb + 4);
        float4 bD = *(const float4*)(b12p + kb + 6);
        f16x8 Bvi = *(const f16x8*)(wvi + kb);
        f16x8 Bvk = *(const f16x8*)(wvk + kb);
        f16x8 Bvm = *(const f16x8*)(wvm + kb);

#define ARG2(CC, B2, TT, RL) fmaf(TT.y, CC.w, fmaf(TT.x, CC.z, fmaf(RL.x, CC.y, B2)))
#define DO_TILE(RL, TT, AC0, AC1, AC2) { \
        float4 a1lo = make_float4(fmaf(RL.y, cc0.x, bA.x), fmaf(RL.y, cc1.x, bA.z), \
                                  fmaf(RL.y, cc2.x, bB.x), fmaf(RL.y, cc3.x, bB.z)); \
        float4 a1hi = make_float4(fmaf(RL.y, cc4.x, bC.x), fmaf(RL.y, cc5.x, bC.z), \
                                  fmaf(RL.y, cc6.x, bD.x), fmaf(RL.y, cc7.x, bD.z)); \
        f16x8 Af1 = rcp8(a1lo, a1hi); \
        float4 a2lo = make_float4(ARG2(cc0, bA.y, TT, RL), ARG2(cc1, bA.w, TT, RL), \
                                  ARG2(cc2, bB.y, TT, RL), ARG2(cc3, bB.w, TT, RL)); \
        float4 a2hi = make_float4(ARG2(cc4, bC.y, TT, RL), ARG2(cc5, bC.w, TT, RL), \
                                  ARG2(cc6, bD.y, TT, RL), ARG2(cc7, bD.w, TT, RL)); \
        f16x8 Af2 = rcp8(a2lo, a2hi); \
        AC0 = __builtin_amdgcn_mfma_f32_16x16x32_f16(Af1, Bvi, AC0, 0, 0, 0); \
        AC1 = __builtin_amdgcn_mfma_f32_16x16x32_f16(Af1, Bvk, AC1, 0, 0, 0); \
        AC2 = __builtin_amdgcn_mfma_f32_16x16x32_f16(Af2, Bvm, AC2, 0, 0, 0); }

        DO_TILE(rl0, tt0, ac0_0, ac1_0, ac2_0)
        DO_TILE(rl1, tt1, ac0_1, ac1_1, ac2_1)
        DO_TILE(rl2, tt2, ac0_2, ac1_2, ac2_2)
        DO_TILE(rl3, tt3, ac0_3, ac1_3, ac2_3)
#undef DO_TILE
#undef ARG2
    }

#define EPI(TC, AC0, AC1, AC2) { \
    long rowbase = (long)TC * NS + s0 + quad * 4; \
    _Pragma("unroll") \
    for (int rg = 0; rg < 4; ++rg) { \
        float vi = fminf(fmaxf(AC0[rg], 0.f), 1.f); \
        float vk = fminf(fmaxf(AC1[rg], 0.f), 1.f); \
        float vm = __builtin_amdgcn_exp2f(AC2[rg]); \
        unsigned pk = (unsigned)(vi * 65535.f + 0.5f) | ((unsigned)(vk * 65535.f + 0.5f) << 16); \
        VMK[(rowbase + rg) * NH + ml] = make_uint2(pk, __float_as_uint(vm)); \
    } }

    EPI(tc0, ac0_0, ac1_0, ac2_0)
    EPI(tc1, ac0_1, ac1_1, ac2_1)
    EPI(tc2, ac0_2, ac1_2, ac2_2)
    EPI(tc3, ac0_3, ac1_3, ac2_3)
#undef EPI

    {
        int tq = t0 + quad; if (tq >= NT) tq = NT - 1;
        const float* xq = X + ((long)tq * NS + srow) * 6;
        float2 peq = *(const float2*)xq;
        float2 ttq = *(const float2*)(xq + 2);
        store_pse(PSE, (long)tq * NS + srow, peq, ttq);
    }
}

// ---------------------------------------------------------------------------
// k_scan v6: 28-deep VMK prefetch ring (was 14). VMK is a 187MB pure-HBM
//   stream: each load is a ~900cy miss, and the 14-step window (~840cy of
//   work) left a residual vmcnt stall on EVERY step at 0.5 waves/SIMD.
//   28-deep doubles the window (~1700cy > 900). PSE stays 14-deep (46KB/block
//   stream -> L2-resident, ~200cy). qr ring keeps mod-14 constant indices;
//   unroll widened to 28 (26*28 + 2 = 730). Numerics identical.
// ---------------------------------------------------------------------------
__global__ __launch_bounds__(64) void k_scan(
    const uint2* __restrict__ VMK, const float4* __restrict__ PSE,
    const float* __restrict__ P8, const float* __restrict__ RKGA,
    _Float16* __restrict__ YH)
{
    int lane = threadIdx.x;
    int s = blockIdx.x * 4 + (lane >> 4);
    int hh = lane & 15;
    size_t ch = (size_t)s * NH + hh;

    const float4* pp = (const float4*)(P8 + (size_t)ch * 8);
    float4 pa = pp[0], pb4 = pp[1];
    float k1 = pa.x, k2 = pa.y, k23 = pa.z, k3 = pa.w;
    float gl = pb4.x, qb = pb4.y, ge1 = pb4.z, ge2 = pb4.w;

    float rk[16];
    {
        const float4* rp = (const float4*)(RKGA + (size_t)ch * 16);
#pragma unroll
        for (int i = 0; i < 4; ++i) {
            float4 v = rp[i];
            rk[4 * i] = v.x; rk[4 * i + 1] = v.y; rk[4 * i + 2] = v.z; rk[4 * i + 3] = v.w;
        }
    }

    float S0 = 0.f, Sv = 0.f, S2 = 0.f, S3 = 0.f;
    float qr[14];
#pragma unroll
    for (int i = 0; i < 14; ++i) qr[i] = 0.f;

    uint2 vb[28]; float4 pbf[14];
#pragma unroll
    for (int i = 0; i < 28; ++i) vb[i] = VMK[(size_t)i * NSNH + ch];
#pragma unroll
    for (int i = 0; i < 14; ++i) pbf[i] = PSE[(size_t)i * NS + s];

    int t = 0;
    // I in 0..27 (vb slot), J = I % 14 (pbf + qr slot) — both compile-time.
#define SBODY(I, J) { \
    uint2 v = vb[I]; float4 ps = pbf[J]; \
    int tv = t + 28; if (tv > NT - 1) tv = NT - 1; \
    int tp = t + 14; if (tp > NT - 1) tp = NT - 1; \
    vb[I] = VMK[(size_t)tv * NSNH + ch]; \
    pbf[J] = PSE[(size_t)tp * NS + s]; \
    float vi = (float)(v.x & 0xffffu) * (1.f / 65535.f); \
    float vk = (float)(v.x >> 16) * (1.f / 65535.f); \
    float vm = __uint_as_float(v.y); \
    float Ps = ps.x, Pl = ps.y, E = ps.z; \
    float H0 = S0 + Ps; \
    float qSm = fminf(H0, vm); S0 = H0 - qSm; \
    float Hv = fmaxf(Sv + Pl * (1.f - vi) - E * ge1, 0.f); \
    float qv = Sv * vk; Sv = Hv - qv; \
    float H2 = fmaxf(S2 + qSm + qv - E * ge2 + Pl * vi, 0.f); \
    float x1 = H2 - gl; \
    float Q1 = (x1 > 0.f) ? __expf(k1 * __logf(x1)) : 0.f; \
    float q2 = fminf(H2, gl) * k2; \
    float Q2 = q2 * (1.f - k23); \
    float H3 = S3 + q2 * k23; \
    float Q3 = H3 * k3 + qb; \
    S2 = H2 - Q1 - q2; S3 = H3 - Q3; \
    float qt = Q1 + Q2 + Q3; \
    float y = qt * rk[0]; \
    _Pragma("unroll") for (int d = 1; d <= 14; ++d) y += qr[((J) + 14 - d) % 14] * rk[d]; \
    qr[J] = qt; \
    YH[(size_t)t * NSNH + ch] = (_Float16)y; \
    ++t; }

    for (int tb = 0; tb < 26; ++tb) {          // 26 * 28 = 728 steps
        SBODY(0, 0)  SBODY(1, 1)  SBODY(2, 2)   SBODY(3, 3)   SBODY(4, 4)   SBODY(5, 5)   SBODY(6, 6)
        SBODY(7, 7)  SBODY(8, 8)  SBODY(9, 9)   SBODY(10, 10) SBODY(11, 11) SBODY(12, 12) SBODY(13, 13)
        SBODY(14, 0) SBODY(15, 1) SBODY(16, 2)  SBODY(17, 3)  SBODY(18, 4)  SBODY(19, 5)  SBODY(20, 6)
        SBODY(21, 7) SBODY(22, 8) SBODY(23, 9)  SBODY(24, 10) SBODY(25, 11) SBODY(26, 12) SBODY(27, 13)
    }
    SBODY(0, 0) SBODY(1, 1)                    // steps 728, 729
#undef SBODY
}

// ---------------------------------------------------------------------------
// k_reduce: OUT[t,s] = sum_h YH[t, s*16+h]. One thread per (t,s); 32 B
//   contiguous per lane -> coalesced 2 KB per wave.
// ---------------------------------------------------------------------------
__global__ __launch_bounds__(256) void k_reduce(
    const _Float16* __restrict__ YH, float* __restrict__ OUT)
{
    long m = (long)blockIdx.x * 256 + threadIdx.x;
    if (m >= (long)NT * NS) return;
    int t = (int)(m / NS), s = (int)(m % NS);
    const _Float16* q = YH + (size_t)t * NSNH + (size_t)s * NH;
    f16x8 a = *(const f16x8*)q;
    f16x8 b = *(const f16x8*)(q + 8);
    float acc = 0.f;
#pragma unroll
    for (int i = 0; i < 8; ++i) acc += (float)a[i];
#pragma unroll
    for (int i = 0; i < 8; ++i) acc += (float)b[i];
    OUT[m] = acc;
}

// ---------------------------------------------------------------------------
extern "C" void kernel_launch(void* const* d_in, const int* in_sizes, int n_in,
                              void* d_out, int out_size, void* d_ws, size_t ws_size,
                              hipStream_t stream)
{
    const float* X    = (const float*)d_in[0];
    const float* XC   = (const float*)d_in[1];
    const float* fcW1 = (const float*)d_in[2];
    const float* fcb1 = (const float*)d_in[3];
    const float* fcW2 = (const float*)d_in[4];
    const float* fcb2 = (const float*)d_in[5];
    const float* fRW1 = (const float*)d_in[6];
    const float* fRb1 = (const float*)d_in[7];
    const float* fRW2 = (const float*)d_in[8];
    const float* fRb2 = (const float*)d_in[9];
    const float* T1W1 = (const float*)d_in[10];
    const float* T1b1 = (const float*)d_in[11];
    const float* T1W2 = (const float*)d_in[12];
    const float* T1b2 = (const float*)d_in[13];
    const float* T2W1 = (const float*)d_in[14];
    const float* T2b1 = (const float*)d_in[15];
    const float* T2W2 = (const float*)d_in[16];
    const float* T2b2 = (const float*)d_in[17];
    float* OUT = (float*)d_out;

    char* w = (char*)d_ws;
    uint2* VMK     = (uint2*)w;     w += (size_t)NT * NSNH * 8;     // 186.9 MB
    float4* PSE    = (float4*)w;    w += (size_t)NT * NS * 16;      // 23.4 MB
    _Float16* YH   = (_Float16*)w;  w += (size_t)NT * NSNH * 2;     // 46.7 MB
    float2* BASE12 = (float2*)w;    w += (size_t)NS * HID * 8;      // 4.1 MB
    float* P8      = (float*)w;     w += (size_t)NS * NH * 8 * 4;
    float* RKGA    = (float*)w;     w += (size_t)NS * NH * 16 * 4;
    _Float16* W2H  = (_Float16*)w;  w += 48 * HID * 2;
    float4* CC4    = (float4*)w;    w += HID * 16;
    float* BIAS48  = (float*)w;     w += 64 * 4;
    (void)ws_size; (void)in_sizes; (void)n_in; (void)out_size;

    k_pack<<<dim3(1), dim3(256), 0, stream>>>(T1W1, T2W1, T1W2, T2W2, T1b2, T2b2,
                                              CC4, W2H, BIAS48);
    k_basin<<<dim3(NS / 4), dim3(256), 0, stream>>>(XC, fcW1, fcb1, fcW2, fcb2,
                                                    fRW1, fRb1, fRW2, fRb2,
                                                    T1W1, T1b1, T2W1, T2b1,
                                                    P8, RKGA, BASE12);
    // grid: s-tiles fastest (x=125, write locality); y = 8-t slab via 2 waves
    // (92 * 2 * 4 = 736 >= 730).
    k_mlp<<<dim3(125, 92), dim3(128), 0, stream>>>(
        X, BASE12, CC4, W2H, BIAS48, VMK, PSE);
    k_scan<<<dim3(NS / 4), dim3(64), 0, stream>>>(VMK, PSE, P8, RKGA, YH);
    k_reduce<<<dim3((unsigned)(((long)NT * NS + 255) / 256)), dim3(256), 0, stream>>>(YH, OUT);
}

// Round 8
// 576.550 us; speedup vs baseline: 1.0399x; 1.0399x over previous
//
#include <hip/hip_runtime.h>
#include <math.h>

#define NT 730
#define NS 2000
#define NH 16
#define NG 32
#define NR 15
#define HID 256
#define NSNH 32000

// 2*log2(e): pre-folded into BASE12/CC4 so the hidden-layer arg is a bare fma.
// tanh(x) = 1 - 2*r, r = rcp(exp2(SC*x)+1). The (1-2r) affine is folded into
// the MFMA weights (W2H = -2*w_f16) and the accumulator init
// (BIAS48 = b + sum_k w_f16), so only r is fed to the matrix core.
#define SC 2.885390081777927f
#define INV6 0.16666666666666666f

typedef _Float16 f16x8 __attribute__((ext_vector_type(8)));
typedef __fp16 fp16v2 __attribute__((ext_vector_type(2)));   // cvt_pkrtz native return type
typedef float f32x4 __attribute__((ext_vector_type(4)));

__device__ __forceinline__ float tanh_pre(float y) {   // y = SC * x
    float e = __builtin_amdgcn_exp2f(y);
    float r = __builtin_amdgcn_rcpf(e + 1.f);
    return fmaf(-2.f, r, 1.f);
}
__device__ __forceinline__ float fast_tanh(float x) { return tanh_pre(x * SC); }
__device__ __forceinline__ float sigmoidf_(float x) { return 1.f / (1.f + __expf(-x)); }

__device__ __forceinline__ float rcp_pre(float y) {    // r = 1/(1+exp2(y)); tanh = 1-2r
    float e = __builtin_amdgcn_exp2f(y);
    return __builtin_amdgcn_rcpf(e + 1.f);
}
__device__ __forceinline__ f16x8 rcp8(float4 lo, float4 hi) {
    union { fp16v2 h[4]; f16x8 v; } u;
    u.h[0] = __builtin_amdgcn_cvt_pkrtz(rcp_pre(lo.x), rcp_pre(lo.y));
    u.h[1] = __builtin_amdgcn_cvt_pkrtz(rcp_pre(lo.z), rcp_pre(lo.w));
    u.h[2] = __builtin_amdgcn_cvt_pkrtz(rcp_pre(hi.x), rcp_pre(hi.y));
    u.h[3] = __builtin_amdgcn_cvt_pkrtz(rcp_pre(hi.z), rcp_pre(hi.w));
    return u.v;
}

// ---------------------------------------------------------------------------
// k_pack: CC4[k] = (SC*a1, SC*c0, SC*c1, SC*c2) interleaved float4.
//   W2H folding: cols 0..31 x(-2/6) (hsig->clamp); cols 32..47 x(-2*SC)
//   (exp->exp2). BIAS48[j] = bias + sum_k (-0.5)*w_f16.
// ---------------------------------------------------------------------------
__global__ __launch_bounds__(256) void k_pack(
    const float* __restrict__ T1W1, const float* __restrict__ T2W1,
    const float* __restrict__ T1W2, const float* __restrict__ T2W2,
    const float* __restrict__ T1b2, const float* __restrict__ T2b2,
    float4* __restrict__ CC4, _Float16* __restrict__ W2H,
    float* __restrict__ BIAS48)
{
    int k = threadIdx.x;
    CC4[k] = make_float4(SC * T1W1[k * (1 + NG)],
                         SC * T2W1[k * (3 + NG)],
                         SC * T2W1[k * (3 + NG) + 1],
                         SC * T2W1[k * (3 + NG) + 2]);
    for (int c = 0; c < 48; ++c) {
        float w = (c < 32) ? (INV6 * T1W2[c * HID + k]) : (SC * T2W2[(c - 32) * HID + k]);
        W2H[c * HID + k] = (_Float16)(-2.f * w);
    }
    if (k < 48) {
        float s = 0.f;
        if (k < 32) {
            for (int i = 0; i < HID; ++i)
                s += -0.5f * (float)(_Float16)(-2.f * INV6 * T1W2[k * HID + i]);
            BIAS48[k] = fmaf(T1b2[k], INV6, 0.5f) + s;
        } else {
            for (int i = 0; i < HID; ++i)
                s += -0.5f * (float)(_Float16)(-2.f * SC * T2W2[(k - 32) * HID + i]);
            BIAS48[k] = SC * T2b2[k - 32] + s;
        }
    }
}

// ---------------------------------------------------------------------------
// k_basin: 4 basins per block; BASE12[s][k] = (SC*b1, SC*b2) interleaved.
// ---------------------------------------------------------------------------
__global__ __launch_bounds__(256) void k_basin(
    const float* __restrict__ XC,
    const float* __restrict__ fcW1, const float* __restrict__ fcb1,
    const float* __restrict__ fcW2, const float* __restrict__ fcb2,
    const float* __restrict__ fRW1, const float* __restrict__ fRb1,
    const float* __restrict__ fRW2, const float* __restrict__ fRb2,
    const float* __restrict__ T1W1, const float* __restrict__ T1b1,
    const float* __restrict__ T2W1, const float* __restrict__ T2b1,
    float* __restrict__ P8, float* __restrict__ RKGA,
    float2* __restrict__ BASE12)
{
    const int s0 = blockIdx.x * 4, tid = threadIdx.x;
    __shared__ float xcs[4][NG];
    __shared__ float h[4][HID], hR[4][HID];
    __shared__ float wbuf[4][10 * NH], wRbuf[4][NH * NR];
    __shared__ float gav[4][NH];

    if (tid < 128) xcs[tid >> 5][tid & 31] = XC[(s0 + (tid >> 5)) * NG + (tid & 31)];
    __syncthreads();

    {
        float ab0 = fcb1[tid], ab1 = ab0, ab2 = ab0, ab3 = ab0;
        float rb0 = fRb1[tid], rb1 = rb0, rb2 = rb0, rb3 = rb0;
        const float4* w4  = (const float4*)(fcW1 + tid * NG);
        const float4* wR4 = (const float4*)(fRW1 + tid * NG);
#pragma unroll
        for (int g = 0; g < NG / 4; ++g) {
            float4 wv = w4[g], rv = wR4[g];
            float4 x0 = *(const float4*)&xcs[0][g * 4];
            float4 x1 = *(const float4*)&xcs[1][g * 4];
            float4 x2 = *(const float4*)&xcs[2][g * 4];
            float4 x3 = *(const float4*)&xcs[3][g * 4];
            ab0 += x0.x*wv.x + x0.y*wv.y + x0.z*wv.z + x0.w*wv.w;
            ab1 += x1.x*wv.x + x1.y*wv.y + x1.z*wv.z + x1.w*wv.w;
            ab2 += x2.x*wv.x + x2.y*wv.y + x2.z*wv.z + x2.w*wv.w;
            ab3 += x3.x*wv.x + x3.y*wv.y + x3.z*wv.z + x3.w*wv.w;
            rb0 += x0.x*rv.x + x0.y*rv.y + x0.z*rv.z + x0.w*rv.w;
            rb1 += x1.x*rv.x + x1.y*rv.y + x1.z*rv.z + x1.w*rv.w;
            rb2 += x2.x*rv.x + x2.y*rv.y + x2.z*rv.z + x2.w*rv.w;
            rb3 += x3.x*rv.x + x3.y*rv.y + x3.z*rv.z + x3.w*rv.w;
        }
        h[0][tid] = fast_tanh(ab0); h[1][tid] = fast_tanh(ab1);
        h[2][tid] = fast_tanh(ab2); h[3][tid] = fast_tanh(ab3);
        hR[0][tid] = fast_tanh(rb0); hR[1][tid] = fast_tanh(rb1);
        hR[2][tid] = fast_tanh(rb2); hR[3][tid] = fast_tanh(rb3);

        float b10 = T1b1[tid], b11 = b10, b12 = b10, b13 = b10;
        float b20 = T2b1[tid], b21 = b20, b22 = b20, b23 = b20;
        const float* w1 = T1W1 + tid * (1 + NG) + 1;
        const float* w2 = T2W1 + tid * (3 + NG) + 3;
#pragma unroll 8
        for (int g = 0; g < NG; ++g) {
            float w1g = w1[g], w2g = w2[g];
            float x0 = xcs[0][g], x1 = xcs[1][g], x2 = xcs[2][g], x3 = xcs[3][g];
            b10 = fmaf(x0, w1g, b10); b11 = fmaf(x1, w1g, b11);
            b12 = fmaf(x2, w1g, b12); b13 = fmaf(x3, w1g, b13);
            b20 = fmaf(x0, w2g, b20); b21 = fmaf(x1, w2g, b21);
            b22 = fmaf(x2, w2g, b22); b23 = fmaf(x3, w2g, b23);
        }
        BASE12[(size_t)(s0 + 0) * HID + tid] = make_float2(SC * b10, SC * b20);
        BASE12[(size_t)(s0 + 1) * HID + tid] = make_float2(SC * b11, SC * b21);
        BASE12[(size_t)(s0 + 2) * HID + tid] = make_float2(SC * b12, SC * b22);
        BASE12[(size_t)(s0 + 3) * HID + tid] = make_float2(SC * b13, SC * b23);
    }
    __syncthreads();

    if (tid < 10 * NH) {
        float a0 = fcb2[tid], a1 = a0, a2 = a0, a3 = a0;
        const float4* w4 = (const float4*)(fcW2 + tid * HID);
        for (int k = 0; k < HID / 4; ++k) {
            float4 wv = w4[k];
            float4 h0 = *(const float4*)&h[0][k * 4];
            float4 h1 = *(const float4*)&h[1][k * 4];
            float4 h2 = *(const float4*)&h[2][k * 4];
            float4 h3 = *(const float4*)&h[3][k * 4];
            a0 += h0.x*wv.x + h0.y*wv.y + h0.z*wv.z + h0.w*wv.w;
            a1 += h1.x*wv.x + h1.y*wv.y + h1.z*wv.z + h1.w*wv.w;
            a2 += h2.x*wv.x + h2.y*wv.y + h2.z*wv.z + h2.w*wv.w;
            a3 += h3.x*wv.x + h3.y*wv.y + h3.z*wv.z + h3.w*wv.w;
        }
        wbuf[0][tid] = a0; wbuf[1][tid] = a1; wbuf[2][tid] = a2; wbuf[3][tid] = a3;
    }
    if (tid < NH * NR) {
        float a0 = fRb2[tid], a1 = a0, a2 = a0, a3 = a0;
        const float4* w4 = (const float4*)(fRW2 + tid * HID);
        for (int k = 0; k < HID / 4; ++k) {
            float4 wv = w4[k];
            float4 h0 = *(const float4*)&hR[0][k * 4];
            float4 h1 = *(const float4*)&hR[1][k * 4];
            float4 h2 = *(const float4*)&hR[2][k * 4];
            float4 h3 = *(const float4*)&hR[3][k * 4];
            a0 += h0.x*wv.x + h0.y*wv.y + h0.z*wv.z + h0.w*wv.w;
            a1 += h1.x*wv.x + h1.y*wv.y + h1.z*wv.z + h1.w*wv.w;
            a2 += h2.x*wv.x + h2.y*wv.y + h2.z*wv.z + h2.w*wv.w;
            a3 += h3.x*wv.x + h3.y*wv.y + h3.z*wv.z + h3.w*wv.w;
        }
        wRbuf[0][tid] = a0; wRbuf[1][tid] = a1; wRbuf[2][tid] = a2; wRbuf[3][tid] = a3;
    }
    __syncthreads();

    if (tid < 64) {
        int b = tid >> 4, hh = tid & 15;
        const float* wb = wbuf[b];
        float mx = -1e30f;
        for (int i = 0; i < NH; ++i) mx = fmaxf(mx, wb[6 * NH + i]);
        float sum = 0.f;
        for (int i = 0; i < NH; ++i) sum += expf(wb[6 * NH + i] - mx);
        gav[b][hh] = expf(wb[6 * NH + hh] - mx) / sum;

        float* p = P8 + (size_t)((s0 + b) * NH + hh) * 8;
        p[0] = sigmoidf_(wb[1 * NH + hh]);
        p[1] = sigmoidf_(wb[2 * NH + hh]);
        p[2] = sigmoidf_(wb[3 * NH + hh]);
        p[3] = sigmoidf_(wb[4 * NH + hh]) * 0.1f;
        p[4] = expf(wb[5 * NH + hh]) * 2.f;
        p[5] = fmaxf(wb[7 * NH + hh], 0.f);
        p[6] = fmaxf(wb[8 * NH + hh], 0.f);
        p[7] = fmaxf(wb[9 * NH + hh], 0.f);
    }
    __syncthreads();

    for (int it = tid; it < 4 * NH * NR; it += 256) {
        int b = it / (NH * NR), r = it % (NH * NR);
        int hh = r / NR, j = r % NR;
        RKGA[(size_t)((s0 + b) * NH + hh) * 16 + (NR - 1 - j)] =
            gav[b][hh] * fmaxf(wRbuf[b][hh * NR + j], 0.f);
    }
}

// ---------------------------------------------------------------------------
// PSE helper (vp partition).
// ---------------------------------------------------------------------------
__device__ __forceinline__ void store_pse(float4* __restrict__ PSE, long m, float2 pe, float2 t12) {
    float P = pe.x, E = pe.y, T1 = t12.x, T2 = t12.y;
    float den = T2 - T1;
    float ratio = (T1 + T2) / ((den == 0.f) ? 1.f : den);
    ratio = fminf(fmaxf(ratio, -1.f), 1.f);
    if ((T1 >= 0.f) || (T2 <= 0.f)) ratio = 0.f;
    float vp = 1.f - acosf(ratio) * (1.f / 3.1415f);
    if (T1 >= 0.f) vp = 1.f;
    if (T2 <= 0.f) vp = 0.f;
    PSE[m] = make_float4(P * (1.f - vp), P * vp, E, 0.f);
}

// ---------------------------------------------------------------------------
// k_mlp v10 (unchanged from R6 best): 2-wave/128-thread blocks, rcp fold,
//   s-fastest grid. 256us, VGPR 88, WRITE 205MB clean.
// ---------------------------------------------------------------------------
__global__ __launch_bounds__(128) void k_mlp(
    const float* __restrict__ X,
    const float2* __restrict__ BASE12, const float4* __restrict__ CC4,
    const _Float16* __restrict__ W2H, const float* __restrict__ BIAS48,
    uint2* __restrict__ VMK, float4* __restrict__ PSE)
{
    const int lane = threadIdx.x & 63;
    const int wave = threadIdx.x >> 6;
    const int quad = lane >> 4, ml = lane & 15;
    const int s0 = blockIdx.x * 16;
    const int t0 = (blockIdx.y * 2 + wave) * 4;
    const int srow = s0 + ml;

    const int tc0 = (t0 < NT) ? t0 : (NT - 1);
    const int tc1 = (t0 + 1 < NT) ? t0 + 1 : (NT - 1);
    const int tc2 = (t0 + 2 < NT) ? t0 + 2 : (NT - 1);
    const int tc3 = (t0 + 3 < NT) ? t0 + 3 : (NT - 1);

    const float* xr0 = X + ((long)tc0 * NS + srow) * 6;
    const float* xr1 = X + ((long)tc1 * NS + srow) * 6;
    const float* xr2 = X + ((long)tc2 * NS + srow) * 6;
    const float* xr3 = X + ((long)tc3 * NS + srow) * 6;
    float2 tt0 = *(const float2*)(xr0 + 2), rl0 = *(const float2*)(xr0 + 4);
    float2 tt1 = *(const float2*)(xr1 + 2), rl1 = *(const float2*)(xr1 + 4);
    float2 tt2 = *(const float2*)(xr2 + 2), rl2 = *(const float2*)(xr2 + 4);
    float2 tt3 = *(const float2*)(xr3 + 2), rl3 = *(const float2*)(xr3 + 4);

    const float bvi = BIAS48[ml];
    const float bvk = BIAS48[NH + ml];
    const float bvm = BIAS48[2 * NH + ml];
    f32x4 ac0_0 = {bvi, bvi, bvi, bvi}, ac0_1 = ac0_0, ac0_2 = ac0_0, ac0_3 = ac0_0;
    f32x4 ac1_0 = {bvk, bvk, bvk, bvk}, ac1_1 = ac1_0, ac1_2 = ac1_0, ac1_3 = ac1_0;
    f32x4 ac2_0 = {bvm, bvm, bvm, bvm}, ac2_1 = ac2_0, ac2_2 = ac2_0, ac2_3 = ac2_0;

    const float2* b12p = BASE12 + (size_t)srow * HID;
    const _Float16* wvi = W2H + (size_t)ml * HID;
    const _Float16* wvk = W2H + (size_t)(NH + ml) * HID;
    const _Float16* wvm = W2H + (size_t)(2 * NH + ml) * HID;

#pragma unroll 2
    for (int ks = 0; ks < 8; ++ks) {
        const int kb = ks * 32 + quad * 8;
        float4 cc0 = CC4[kb], cc1 = CC4[kb + 1], cc2 = CC4[kb + 2], cc3 = CC4[kb + 3];
        float4 cc4 = CC4[kb + 4], cc5 = CC4[kb + 5], cc6 = CC4[kb + 6], cc7 = CC4[kb + 7];
        float4 bA = *(const float4*)(b12p + kb);       // b1[k],b2[k],b1[k+1],b2[k+1]
        float4 bB = *(const float4*)(b12p + kb + 2);
        float4 bC = *(const float4*)(b12p + kb + 4);
        float4 bD = *(const float4*)(b12p + kb + 6);
        f16x8 Bvi = *(const f16x8*)(wvi + kb);
        f16x8 Bvk = *(const f16x8*)(wvk + kb);
        f16x8 Bvm = *(const f16x8*)(wvm + kb);

#define ARG2(CC, B2, TT, RL) fmaf(TT.y, CC.w, fmaf(TT.x, CC.z, fmaf(RL.x, CC.y, B2)))
#define DO_TILE(RL, TT, AC0, AC1, AC2) { \
        float4 a1lo = make_float4(fmaf(RL.y, cc0.x, bA.x), fmaf(RL.y, cc1.x, bA.z), \
                                  fmaf(RL.y, cc2.x, bB.x), fmaf(RL.y, cc3.x, bB.z)); \
        float4 a1hi = make_float4(fmaf(RL.y, cc4.x, bC.x), fmaf(RL.y, cc5.x, bC.z), \
                                  fmaf(RL.y, cc6.x, bD.x), fmaf(RL.y, cc7.x, bD.z)); \
        f16x8 Af1 = rcp8(a1lo, a1hi); \
        float4 a2lo = make_float4(ARG2(cc0, bA.y, TT, RL), ARG2(cc1, bA.w, TT, RL), \
                                  ARG2(cc2, bB.y, TT, RL), ARG2(cc3, bB.w, TT, RL)); \
        float4 a2hi = make_float4(ARG2(cc4, bC.y, TT, RL), ARG2(cc5, bC.w, TT, RL), \
                                  ARG2(cc6, bD.y, TT, RL), ARG2(cc7, bD.w, TT, RL)); \
        f16x8 Af2 = rcp8(a2lo, a2hi); \
        AC0 = __builtin_amdgcn_mfma_f32_16x16x32_f16(Af1, Bvi, AC0, 0, 0, 0); \
        AC1 = __builtin_amdgcn_mfma_f32_16x16x32_f16(Af1, Bvk, AC1, 0, 0, 0); \
        AC2 = __builtin_amdgcn_mfma_f32_16x16x32_f16(Af2, Bvm, AC2, 0, 0, 0); }

        DO_TILE(rl0, tt0, ac0_0, ac1_0, ac2_0)
        DO_TILE(rl1, tt1, ac0_1, ac1_1, ac2_1)
        DO_TILE(rl2, tt2, ac0_2, ac1_2, ac2_2)
        DO_TILE(rl3, tt3, ac0_3, ac1_3, ac2_3)
#undef DO_TILE
#undef ARG2
    }

#define EPI(TC, AC0, AC1, AC2) { \
    long rowbase = (long)TC * NS + s0 + quad * 4; \
    _Pragma("unroll") \
    for (int rg = 0; rg < 4; ++rg) { \
        float vi = fminf(fmaxf(AC0[rg], 0.f), 1.f); \
        float vk = fminf(fmaxf(AC1[rg], 0.f), 1.f); \
        float vm = __builtin_amdgcn_exp2f(AC2[rg]); \
        unsigned pk = (unsigned)(vi * 65535.f + 0.5f) | ((unsigned)(vk * 65535.f + 0.5f) << 16); \
        VMK[(rowbase + rg) * NH + ml] = make_uint2(pk, __float_as_uint(vm)); \
    } }

    EPI(tc0, ac0_0, ac1_0, ac2_0)
    EPI(tc1, ac0_1, ac1_1, ac2_1)
    EPI(tc2, ac0_2, ac1_2, ac2_2)
    EPI(tc3, ac0_3, ac1_3, ac2_3)
#undef EPI

    {
        int tq = t0 + quad; if (tq >= NT) tq = NT - 1;
        const float* xq = X + ((long)tq * NS + srow) * 6;
        float2 peq = *(const float2*)xq;
        float2 ttq = *(const float2*)(xq + 2);
        store_pse(PSE, (long)tq * NS + srow, peq, ttq);
    }
}

// ---------------------------------------------------------------------------
// k_scan v7: TWO channels per lane (adjacent h of the same basin) — fills the
//   dependent-latency bubbles that dominate at ~0.5 waves/SIMD (R4's shuffle
//   probe measured ~60cy per dependent op; R7 showed prefetch depth can't
//   help: vmcnt maxes at 63 and the chain, not the loads, is the floor).
//   Lane = b*8+hl handles ch0 = (s0+b)*16 + 2*hl and ch0+1:
//   - VMK read: ONE uint4 (both channels, 16B) -> wave reads 1KB contiguous;
//   - YH write: one packed 4B store (two RTN f16 via union — numerics
//     unchanged vs scalar stores);
//   - PSE ring shared (same s). 14-deep rings; vmem ops/step = 3 ->
//     42 outstanding max, inside the 63 limit.
//   Per-channel op order identical to v4 -> bitwise-same YH values.
// ---------------------------------------------------------------------------
__global__ __launch_bounds__(64) void k_scan(
    const uint2* __restrict__ VMK, const float4* __restrict__ PSE,
    const float* __restrict__ P8, const float* __restrict__ RKGA,
    _Float16* __restrict__ YH)
{
    int lane = threadIdx.x;
    int b = lane >> 3, hl = lane & 7;
    int s = blockIdx.x * 8 + b;
    size_t ch0 = (size_t)s * NH + 2 * hl;          // even channel; odd = ch0+1

    const float4* ppA = (const float4*)(P8 + ch0 * 8);
    const float4* ppB = (const float4*)(P8 + (ch0 + 1) * 8);
    float4 paA = ppA[0], pbA = ppA[1];
    float4 paB = ppB[0], pbB = ppB[1];
    float k1A = paA.x, k2A = paA.y, k23A = paA.z, k3A = paA.w;
    float glA = pbA.x, qbA = pbA.y, ge1A = pbA.z, ge2A = pbA.w;
    float k1B = paB.x, k2B = paB.y, k23B = paB.z, k3B = paB.w;
    float glB = pbB.x, qbB = pbB.y, ge1B = pbB.z, ge2B = pbB.w;

    float rkA[16], rkB[16];
    {
        const float4* rpA = (const float4*)(RKGA + ch0 * 16);
        const float4* rpB = (const float4*)(RKGA + (ch0 + 1) * 16);
#pragma unroll
        for (int i = 0; i < 4; ++i) {
            float4 vA = rpA[i], vB = rpB[i];
            rkA[4*i] = vA.x; rkA[4*i+1] = vA.y; rkA[4*i+2] = vA.z; rkA[4*i+3] = vA.w;
            rkB[4*i] = vB.x; rkB[4*i+1] = vB.y; rkB[4*i+2] = vB.z; rkB[4*i+3] = vB.w;
        }
    }

    float S0A = 0.f, SvA = 0.f, S2A = 0.f, S3A = 0.f;
    float S0B = 0.f, SvB = 0.f, S2B = 0.f, S3B = 0.f;
    float qrA[14], qrB[14];
#pragma unroll
    for (int i = 0; i < 14; ++i) { qrA[i] = 0.f; qrB[i] = 0.f; }

    uint4 vb[14]; float4 pbf[14];
#pragma unroll
    for (int i = 0; i < 14; ++i) {
        vb[i] = *(const uint4*)(VMK + (size_t)i * NSNH + ch0);
        pbf[i] = PSE[(size_t)i * NS + s];
    }

    int t = 0;
#define SBODY(I) { \
    uint4 v = vb[I]; float4 ps = pbf[I]; \
    int t2 = t + 14; if (t2 > NT - 1) t2 = NT - 1; \
    vb[I] = *(const uint4*)(VMK + (size_t)t2 * NSNH + ch0); \
    pbf[I] = PSE[(size_t)t2 * NS + s]; \
    float Ps = ps.x, Pl = ps.y, E = ps.z; \
    float viA = (float)(v.x & 0xffffu) * (1.f / 65535.f); \
    float vkA = (float)(v.x >> 16) * (1.f / 65535.f); \
    float vmA = __uint_as_float(v.y); \
    float viB = (float)(v.z & 0xffffu) * (1.f / 65535.f); \
    float vkB = (float)(v.z >> 16) * (1.f / 65535.f); \
    float vmB = __uint_as_float(v.w); \
    float H0A = S0A + Ps; \
    float qSmA = fminf(H0A, vmA); S0A = H0A - qSmA; \
    float HvA = fmaxf(SvA + Pl * (1.f - viA) - E * ge1A, 0.f); \
    float qvA = SvA * vkA; SvA = HvA - qvA; \
    float H2A = fmaxf(S2A + qSmA + qvA - E * ge2A + Pl * viA, 0.f); \
    float x1A = H2A - glA; \
    float Q1A = (x1A > 0.f) ? __expf(k1A * __logf(x1A)) : 0.f; \
    float q2A = fminf(H2A, glA) * k2A; \
    float Q2A = q2A * (1.f - k23A); \
    float H3A = S3A + q2A * k23A; \
    float Q3A = H3A * k3A + qbA; \
    S2A = H2A - Q1A - q2A; S3A = H3A - Q3A; \
    float qtA = Q1A + Q2A + Q3A; \
    float H0B = S0B + Ps; \
    float qSmB = fminf(H0B, vmB); S0B = H0B - qSmB; \
    float HvB = fmaxf(SvB + Pl * (1.f - viB) - E * ge1B, 0.f); \
    float qvB = SvB * vkB; SvB = HvB - qvB; \
    float H2B = fmaxf(S2B + qSmB + qvB - E * ge2B + Pl * viB, 0.f); \
    float x1B = H2B - glB; \
    float Q1B = (x1B > 0.f) ? __expf(k1B * __logf(x1B)) : 0.f; \
    float q2B = fminf(H2B, glB) * k2B; \
    float Q2B = q2B * (1.f - k23B); \
    float H3B = S3B + q2B * k23B; \
    float Q3B = H3B * k3B + qbB; \
    S2B = H2B - Q1B - q2B; S3B = H3B - Q3B; \
    float qtB = Q1B + Q2B + Q3B; \
    float yA = qtA * rkA[0]; \
    float yB = qtB * rkB[0]; \
    _Pragma("unroll") for (int d = 1; d <= 14; ++d) { \
        yA += qrA[((I) + 14 - d) % 14] * rkA[d]; \
        yB += qrB[((I) + 14 - d) % 14] * rkB[d]; } \
    qrA[I] = qtA; qrB[I] = qtB; \
    union { _Float16 h[2]; unsigned u; } yu; \
    yu.h[0] = (_Float16)yA; yu.h[1] = (_Float16)yB; \
    *(unsigned*)(YH + (size_t)t * NSNH + ch0) = yu.u; \
    ++t; }

    for (int tb = 0; tb < 52; ++tb) {          // 52 * 14 = 728 steps
        SBODY(0) SBODY(1) SBODY(2) SBODY(3) SBODY(4) SBODY(5) SBODY(6)
        SBODY(7) SBODY(8) SBODY(9) SBODY(10) SBODY(11) SBODY(12) SBODY(13)
    }
    SBODY(0) SBODY(1)                          // steps 728, 729
#undef SBODY
}

// ---------------------------------------------------------------------------
// k_reduce: OUT[t,s] = sum_h YH[t, s*16+h]. One thread per (t,s); 32 B
//   contiguous per lane -> coalesced 2 KB per wave.
// ---------------------------------------------------------------------------
__global__ __launch_bounds__(256) void k_reduce(
    const _Float16* __restrict__ YH, float* __restrict__ OUT)
{
    long m = (long)blockIdx.x * 256 + threadIdx.x;
    if (m >= (long)NT * NS) return;
    int t = (int)(m / NS), s = (int)(m % NS);
    const _Float16* q = YH + (size_t)t * NSNH + (size_t)s * NH;
    f16x8 a = *(const f16x8*)q;
    f16x8 b = *(const f16x8*)(q + 8);
    float acc = 0.f;
#pragma unroll
    for (int i = 0; i < 8; ++i) acc += (float)a[i];
#pragma unroll
    for (int i = 0; i < 8; ++i) acc += (float)b[i];
    OUT[m] = acc;
}

// ---------------------------------------------------------------------------
extern "C" void kernel_launch(void* const* d_in, const int* in_sizes, int n_in,
                              void* d_out, int out_size, void* d_ws, size_t ws_size,
                              hipStream_t stream)
{
    const float* X    = (const float*)d_in[0];
    const float* XC   = (const float*)d_in[1];
    const float* fcW1 = (const float*)d_in[2];
    const float* fcb1 = (const float*)d_in[3];
    const float* fcW2 = (const float*)d_in[4];
    const float* fcb2 = (const float*)d_in[5];
    const float* fRW1 = (const float*)d_in[6];
    const float* fRb1 = (const float*)d_in[7];
    const float* fRW2 = (const float*)d_in[8];
    const float* fRb2 = (const float*)d_in[9];
    const float* T1W1 = (const float*)d_in[10];
    const float* T1b1 = (const float*)d_in[11];
    const float* T1W2 = (const float*)d_in[12];
    const float* T1b2 = (const float*)d_in[13];
    const float* T2W1 = (const float*)d_in[14];
    const float* T2b1 = (const float*)d_in[15];
    const float* T2W2 = (const float*)d_in[16];
    const float* T2b2 = (const float*)d_in[17];
    float* OUT = (float*)d_out;

    char* w = (char*)d_ws;
    uint2* VMK     = (uint2*)w;     w += (size_t)NT * NSNH * 8;     // 186.9 MB
    float4* PSE    = (float4*)w;    w += (size_t)NT * NS * 16;      // 23.4 MB
    _Float16* YH   = (_Float16*)w;  w += (size_t)NT * NSNH * 2;     // 46.7 MB
    float2* BASE12 = (float2*)w;    w += (size_t)NS * HID * 8;      // 4.1 MB
    float* P8      = (float*)w;     w += (size_t)NS * NH * 8 * 4;
    float* RKGA    = (float*)w;     w += (size_t)NS * NH * 16 * 4;
    _Float16* W2H  = (_Float16*)w;  w += 48 * HID * 2;
    float4* CC4    = (float4*)w;    w += HID * 16;
    float* BIAS48  = (float*)w;     w += 64 * 4;
    (void)ws_size; (void)in_sizes; (void)n_in; (void)out_size;

    k_pack<<<dim3(1), dim3(256), 0, stream>>>(T1W1, T2W1, T1W2, T2W2, T1b2, T2b2,
                                              CC4, W2H, BIAS48);
    k_basin<<<dim3(NS / 4), dim3(256), 0, stream>>>(XC, fcW1, fcb1, fcW2, fcb2,
                                                    fRW1, fRb1, fRW2, fRb2,
                                                    T1W1, T1b1, T2W1, T2b1,
                                                    P8, RKGA, BASE12);
    // grid: s-tiles fastest (x=125, write locality); y = 8-t slab via 2 waves
    // (92 * 2 * 4 = 736 >= 730).
    k_mlp<<<dim3(125, 92), dim3(128), 0, stream>>>(
        X, BASE12, CC4, W2H, BIAS48, VMK, PSE);
    k_scan<<<dim3(NS / 8), dim3(64), 0, stream>>>(VMK, PSE, P8, RKGA, YH);
    k_reduce<<<dim3((unsigned)(((long)NT * NS + 255) / 256)), dim3(256), 0, stream>>>(YH, OUT);
}

// Round 9
// 540.992 us; speedup vs baseline: 1.1082x; 1.0657x over previous
//
#include <hip/hip_runtime.h>
#include <math.h>

#define NT 730
#define NS 2000
#define NH 16
#define NG 32
#define NR 15
#define HID 256
#define NSNH 32000

// 2*log2(e): pre-folded into BASE12/CC4 so the hidden-layer arg is a bare fma.
// tanh(x) = 1 - 2*r, r = rcp(exp2(SC*x)+1). The (1-2r) affine is folded into
// the MFMA weights (W2H = -2*w_f16) and the accumulator init
// (BIAS48 = b + sum_k w_f16), so only r is fed to the matrix core.
#define SC 2.885390081777927f
#define INV6 0.16666666666666666f

typedef _Float16 f16x8 __attribute__((ext_vector_type(8)));
typedef __fp16 fp16v2 __attribute__((ext_vector_type(2)));   // cvt_pkrtz native return type
typedef float f32x4 __attribute__((ext_vector_type(4)));

__device__ __forceinline__ float tanh_pre(float y) {   // y = SC * x
    float e = __builtin_amdgcn_exp2f(y);
    float r = __builtin_amdgcn_rcpf(e + 1.f);
    return fmaf(-2.f, r, 1.f);
}
__device__ __forceinline__ float fast_tanh(float x) { return tanh_pre(x * SC); }
__device__ __forceinline__ float sigmoidf_(float x) { return 1.f / (1.f + __expf(-x)); }

__device__ __forceinline__ float rcp_pre(float y) {    // r = 1/(1+exp2(y)); tanh = 1-2r
    float e = __builtin_amdgcn_exp2f(y);
    return __builtin_amdgcn_rcpf(e + 1.f);
}
__device__ __forceinline__ f16x8 rcp8(float4 lo, float4 hi) {
    union { fp16v2 h[4]; f16x8 v; } u;
    u.h[0] = __builtin_amdgcn_cvt_pkrtz(rcp_pre(lo.x), rcp_pre(lo.y));
    u.h[1] = __builtin_amdgcn_cvt_pkrtz(rcp_pre(lo.z), rcp_pre(lo.w));
    u.h[2] = __builtin_amdgcn_cvt_pkrtz(rcp_pre(hi.x), rcp_pre(hi.y));
    u.h[3] = __builtin_amdgcn_cvt_pkrtz(rcp_pre(hi.z), rcp_pre(hi.w));
    return u.v;
}

// ---------------------------------------------------------------------------
// k_pack: CC4[k] = (SC*a1, SC*c0, SC*c1, SC*c2) interleaved float4.
//   W2H folding: cols 0..31 x(-2/6) (hsig->clamp); cols 32..47 x(-2*SC)
//   (exp->exp2). BIAS48[j] = bias + sum_k (-0.5)*w_f16.
// ---------------------------------------------------------------------------
__global__ __launch_bounds__(256) void k_pack(
    const float* __restrict__ T1W1, const float* __restrict__ T2W1,
    const float* __restrict__ T1W2, const float* __restrict__ T2W2,
    const float* __restrict__ T1b2, const float* __restrict__ T2b2,
    float4* __restrict__ CC4, _Float16* __restrict__ W2H,
    float* __restrict__ BIAS48)
{
    int k = threadIdx.x;
    CC4[k] = make_float4(SC * T1W1[k * (1 + NG)],
                         SC * T2W1[k * (3 + NG)],
                         SC * T2W1[k * (3 + NG) + 1],
                         SC * T2W1[k * (3 + NG) + 2]);
    for (int c = 0; c < 48; ++c) {
        float w = (c < 32) ? (INV6 * T1W2[c * HID + k]) : (SC * T2W2[(c - 32) * HID + k]);
        W2H[c * HID + k] = (_Float16)(-2.f * w);
    }
    if (k < 48) {
        float s = 0.f;
        if (k < 32) {
            for (int i = 0; i < HID; ++i)
                s += -0.5f * (float)(_Float16)(-2.f * INV6 * T1W2[k * HID + i]);
            BIAS48[k] = fmaf(T1b2[k], INV6, 0.5f) + s;
        } else {
            for (int i = 0; i < HID; ++i)
                s += -0.5f * (float)(_Float16)(-2.f * SC * T2W2[(k - 32) * HID + i]);
            BIAS48[k] = SC * T2b2[k - 32] + s;
        }
    }
}

// ---------------------------------------------------------------------------
// k_basin: 4 basins per block; BASE12[s][k] = (SC*b1, SC*b2) interleaved.
// ---------------------------------------------------------------------------
__global__ __launch_bounds__(256) void k_basin(
    const float* __restrict__ XC,
    const float* __restrict__ fcW1, const float* __restrict__ fcb1,
    const float* __restrict__ fcW2, const float* __restrict__ fcb2,
    const float* __restrict__ fRW1, const float* __restrict__ fRb1,
    const float* __restrict__ fRW2, const float* __restrict__ fRb2,
    const float* __restrict__ T1W1, const float* __restrict__ T1b1,
    const float* __restrict__ T2W1, const float* __restrict__ T2b1,
    float* __restrict__ P8, float* __restrict__ RKGA,
    float2* __restrict__ BASE12)
{
    const int s0 = blockIdx.x * 4, tid = threadIdx.x;
    __shared__ float xcs[4][NG];
    __shared__ float h[4][HID], hR[4][HID];
    __shared__ float wbuf[4][10 * NH], wRbuf[4][NH * NR];
    __shared__ float gav[4][NH];

    if (tid < 128) xcs[tid >> 5][tid & 31] = XC[(s0 + (tid >> 5)) * NG + (tid & 31)];
    __syncthreads();

    {
        float ab0 = fcb1[tid], ab1 = ab0, ab2 = ab0, ab3 = ab0;
        float rb0 = fRb1[tid], rb1 = rb0, rb2 = rb0, rb3 = rb0;
        const float4* w4  = (const float4*)(fcW1 + tid * NG);
        const float4* wR4 = (const float4*)(fRW1 + tid * NG);
#pragma unroll
        for (int g = 0; g < NG / 4; ++g) {
            float4 wv = w4[g], rv = wR4[g];
            float4 x0 = *(const float4*)&xcs[0][g * 4];
            float4 x1 = *(const float4*)&xcs[1][g * 4];
            float4 x2 = *(const float4*)&xcs[2][g * 4];
            float4 x3 = *(const float4*)&xcs[3][g * 4];
            ab0 += x0.x*wv.x + x0.y*wv.y + x0.z*wv.z + x0.w*wv.w;
            ab1 += x1.x*wv.x + x1.y*wv.y + x1.z*wv.z + x1.w*wv.w;
            ab2 += x2.x*wv.x + x2.y*wv.y + x2.z*wv.z + x2.w*wv.w;
            ab3 += x3.x*wv.x + x3.y*wv.y + x3.z*wv.z + x3.w*wv.w;
            rb0 += x0.x*rv.x + x0.y*rv.y + x0.z*rv.z + x0.w*rv.w;
            rb1 += x1.x*rv.x + x1.y*rv.y + x1.z*rv.z + x1.w*rv.w;
            rb2 += x2.x*rv.x + x2.y*rv.y + x2.z*rv.z + x2.w*rv.w;
            rb3 += x3.x*rv.x + x3.y*rv.y + x3.z*rv.z + x3.w*rv.w;
        }
        h[0][tid] = fast_tanh(ab0); h[1][tid] = fast_tanh(ab1);
        h[2][tid] = fast_tanh(ab2); h[3][tid] = fast_tanh(ab3);
        hR[0][tid] = fast_tanh(rb0); hR[1][tid] = fast_tanh(rb1);
        hR[2][tid] = fast_tanh(rb2); hR[3][tid] = fast_tanh(rb3);

        float b10 = T1b1[tid], b11 = b10, b12 = b10, b13 = b10;
        float b20 = T2b1[tid], b21 = b20, b22 = b20, b23 = b20;
        const float* w1 = T1W1 + tid * (1 + NG) + 1;
        const float* w2 = T2W1 + tid * (3 + NG) + 3;
#pragma unroll 8
        for (int g = 0; g < NG; ++g) {
            float w1g = w1[g], w2g = w2[g];
            float x0 = xcs[0][g], x1 = xcs[1][g], x2 = xcs[2][g], x3 = xcs[3][g];
            b10 = fmaf(x0, w1g, b10); b11 = fmaf(x1, w1g, b11);
            b12 = fmaf(x2, w1g, b12); b13 = fmaf(x3, w1g, b13);
            b20 = fmaf(x0, w2g, b20); b21 = fmaf(x1, w2g, b21);
            b22 = fmaf(x2, w2g, b22); b23 = fmaf(x3, w2g, b23);
        }
        BASE12[(size_t)(s0 + 0) * HID + tid] = make_float2(SC * b10, SC * b20);
        BASE12[(size_t)(s0 + 1) * HID + tid] = make_float2(SC * b11, SC * b21);
        BASE12[(size_t)(s0 + 2) * HID + tid] = make_float2(SC * b12, SC * b22);
        BASE12[(size_t)(s0 + 3) * HID + tid] = make_float2(SC * b13, SC * b23);
    }
    __syncthreads();

    if (tid < 10 * NH) {
        float a0 = fcb2[tid], a1 = a0, a2 = a0, a3 = a0;
        const float4* w4 = (const float4*)(fcW2 + tid * HID);
        for (int k = 0; k < HID / 4; ++k) {
            float4 wv = w4[k];
            float4 h0 = *(const float4*)&h[0][k * 4];
            float4 h1 = *(const float4*)&h[1][k * 4];
            float4 h2 = *(const float4*)&h[2][k * 4];
            float4 h3 = *(const float4*)&h[3][k * 4];
            a0 += h0.x*wv.x + h0.y*wv.y + h0.z*wv.z + h0.w*wv.w;
            a1 += h1.x*wv.x + h1.y*wv.y + h1.z*wv.z + h1.w*wv.w;
            a2 += h2.x*wv.x + h2.y*wv.y + h2.z*wv.z + h2.w*wv.w;
            a3 += h3.x*wv.x + h3.y*wv.y + h3.z*wv.z + h3.w*wv.w;
        }
        wbuf[0][tid] = a0; wbuf[1][tid] = a1; wbuf[2][tid] = a2; wbuf[3][tid] = a3;
    }
    if (tid < NH * NR) {
        float a0 = fRb2[tid], a1 = a0, a2 = a0, a3 = a0;
        const float4* w4 = (const float4*)(fRW2 + tid * HID);
        for (int k = 0; k < HID / 4; ++k) {
            float4 wv = w4[k];
            float4 h0 = *(const float4*)&hR[0][k * 4];
            float4 h1 = *(const float4*)&hR[1][k * 4];
            float4 h2 = *(const float4*)&hR[2][k * 4];
            float4 h3 = *(const float4*)&hR[3][k * 4];
            a0 += h0.x*wv.x + h0.y*wv.y + h0.z*wv.z + h0.w*wv.w;
            a1 += h1.x*wv.x + h1.y*wv.y + h1.z*wv.z + h1.w*wv.w;
            a2 += h2.x*wv.x + h2.y*wv.y + h2.z*wv.z + h2.w*wv.w;
            a3 += h3.x*wv.x + h3.y*wv.y + h3.z*wv.z + h3.w*wv.w;
        }
        wRbuf[0][tid] = a0; wRbuf[1][tid] = a1; wRbuf[2][tid] = a2; wRbuf[3][tid] = a3;
    }
    __syncthreads();

    if (tid < 64) {
        int b = tid >> 4, hh = tid & 15;
        const float* wb = wbuf[b];
        float mx = -1e30f;
        for (int i = 0; i < NH; ++i) mx = fmaxf(mx, wb[6 * NH + i]);
        float sum = 0.f;
        for (int i = 0; i < NH; ++i) sum += expf(wb[6 * NH + i] - mx);
        gav[b][hh] = expf(wb[6 * NH + hh] - mx) / sum;

        float* p = P8 + (size_t)((s0 + b) * NH + hh) * 8;
        p[0] = sigmoidf_(wb[1 * NH + hh]);
        p[1] = sigmoidf_(wb[2 * NH + hh]);
        p[2] = sigmoidf_(wb[3 * NH + hh]);
        p[3] = sigmoidf_(wb[4 * NH + hh]) * 0.1f;
        p[4] = expf(wb[5 * NH + hh]) * 2.f;
        p[5] = fmaxf(wb[7 * NH + hh], 0.f);
        p[6] = fmaxf(wb[8 * NH + hh], 0.f);
        p[7] = fmaxf(wb[9 * NH + hh], 0.f);
    }
    __syncthreads();

    for (int it = tid; it < 4 * NH * NR; it += 256) {
        int b = it / (NH * NR), r = it % (NH * NR);
        int hh = r / NR, j = r % NR;
        RKGA[(size_t)((s0 + b) * NH + hh) * 16 + (NR - 1 - j)] =
            gav[b][hh] * fmaxf(wRbuf[b][hh * NR + j], 0.f);
    }
}

// ---------------------------------------------------------------------------
// PSE helper (vp partition).
// ---------------------------------------------------------------------------
__device__ __forceinline__ void store_pse(float4* __restrict__ PSE, long m, float2 pe, float2 t12) {
    float P = pe.x, E = pe.y, T1 = t12.x, T2 = t12.y;
    float den = T2 - T1;
    float ratio = (T1 + T2) / ((den == 0.f) ? 1.f : den);
    ratio = fminf(fmaxf(ratio, -1.f), 1.f);
    if ((T1 >= 0.f) || (T2 <= 0.f)) ratio = 0.f;
    float vp = 1.f - acosf(ratio) * (1.f / 3.1415f);
    if (T1 >= 0.f) vp = 1.f;
    if (T2 <= 0.f) vp = 0.f;
    PSE[m] = make_float4(P * (1.f - vp), P * vp, E, 0.f);
}

// ---------------------------------------------------------------------------
// k_mlp v10 (unchanged, R6 best): 2-wave/128-thread blocks, rcp fold,
//   s-fastest grid. 254us, VGPR 88, WRITE 205MB clean.
// ---------------------------------------------------------------------------
__global__ __launch_bounds__(128) void k_mlp(
    const float* __restrict__ X,
    const float2* __restrict__ BASE12, const float4* __restrict__ CC4,
    const _Float16* __restrict__ W2H, const float* __restrict__ BIAS48,
    uint2* __restrict__ VMK, float4* __restrict__ PSE)
{
    const int lane = threadIdx.x & 63;
    const int wave = threadIdx.x >> 6;
    const int quad = lane >> 4, ml = lane & 15;
    const int s0 = blockIdx.x * 16;
    const int t0 = (blockIdx.y * 2 + wave) * 4;
    const int srow = s0 + ml;

    const int tc0 = (t0 < NT) ? t0 : (NT - 1);
    const int tc1 = (t0 + 1 < NT) ? t0 + 1 : (NT - 1);
    const int tc2 = (t0 + 2 < NT) ? t0 + 2 : (NT - 1);
    const int tc3 = (t0 + 3 < NT) ? t0 + 3 : (NT - 1);

    const float* xr0 = X + ((long)tc0 * NS + srow) * 6;
    const float* xr1 = X + ((long)tc1 * NS + srow) * 6;
    const float* xr2 = X + ((long)tc2 * NS + srow) * 6;
    const float* xr3 = X + ((long)tc3 * NS + srow) * 6;
    float2 tt0 = *(const float2*)(xr0 + 2), rl0 = *(const float2*)(xr0 + 4);
    float2 tt1 = *(const float2*)(xr1 + 2), rl1 = *(const float2*)(xr1 + 4);
    float2 tt2 = *(const float2*)(xr2 + 2), rl2 = *(const float2*)(xr2 + 4);
    float2 tt3 = *(const float2*)(xr3 + 2), rl3 = *(const float2*)(xr3 + 4);

    const float bvi = BIAS48[ml];
    const float bvk = BIAS48[NH + ml];
    const float bvm = BIAS48[2 * NH + ml];
    f32x4 ac0_0 = {bvi, bvi, bvi, bvi}, ac0_1 = ac0_0, ac0_2 = ac0_0, ac0_3 = ac0_0;
    f32x4 ac1_0 = {bvk, bvk, bvk, bvk}, ac1_1 = ac1_0, ac1_2 = ac1_0, ac1_3 = ac1_0;
    f32x4 ac2_0 = {bvm, bvm, bvm, bvm}, ac2_1 = ac2_0, ac2_2 = ac2_0, ac2_3 = ac2_0;

    const float2* b12p = BASE12 + (size_t)srow * HID;
    const _Float16* wvi = W2H + (size_t)ml * HID;
    const _Float16* wvk = W2H + (size_t)(NH + ml) * HID;
    const _Float16* wvm = W2H + (size_t)(2 * NH + ml) * HID;

#pragma unroll 2
    for (int ks = 0; ks < 8; ++ks) {
        const int kb = ks * 32 + quad * 8;
        float4 cc0 = CC4[kb], cc1 = CC4[kb + 1], cc2 = CC4[kb + 2], cc3 = CC4[kb + 3];
        float4 cc4 = CC4[kb + 4], cc5 = CC4[kb + 5], cc6 = CC4[kb + 6], cc7 = CC4[kb + 7];
        float4 bA = *(const float4*)(b12p + kb);       // b1[k],b2[k],b1[k+1],b2[k+1]
        float4 bB = *(const float4*)(b12p + kb + 2);
        float4 bC = *(const float4*)(b12p + kb + 4);
        float4 bD = *(const float4*)(b12p + kb + 6);
        f16x8 Bvi = *(const f16x8*)(wvi + kb);
        f16x8 Bvk = *(const f16x8*)(wvk + kb);
        f16x8 Bvm = *(const f16x8*)(wvm + kb);

#define ARG2(CC, B2, TT, RL) fmaf(TT.y, CC.w, fmaf(TT.x, CC.z, fmaf(RL.x, CC.y, B2)))
#define DO_TILE(RL, TT, AC0, AC1, AC2) { \
        float4 a1lo = make_float4(fmaf(RL.y, cc0.x, bA.x), fmaf(RL.y, cc1.x, bA.z), \
                                  fmaf(RL.y, cc2.x, bB.x), fmaf(RL.y, cc3.x, bB.z)); \
        float4 a1hi = make_float4(fmaf(RL.y, cc4.x, bC.x), fmaf(RL.y, cc5.x, bC.z), \
                                  fmaf(RL.y, cc6.x, bD.x), fmaf(RL.y, cc7.x, bD.z)); \
        f16x8 Af1 = rcp8(a1lo, a1hi); \
        float4 a2lo = make_float4(ARG2(cc0, bA.y, TT, RL), ARG2(cc1, bA.w, TT, RL), \
                                  ARG2(cc2, bB.y, TT, RL), ARG2(cc3, bB.w, TT, RL)); \
        float4 a2hi = make_float4(ARG2(cc4, bC.y, TT, RL), ARG2(cc5, bC.w, TT, RL), \
                                  ARG2(cc6, bD.y, TT, RL), ARG2(cc7, bD.w, TT, RL)); \
        f16x8 Af2 = rcp8(a2lo, a2hi); \
        AC0 = __builtin_amdgcn_mfma_f32_16x16x32_f16(Af1, Bvi, AC0, 0, 0, 0); \
        AC1 = __builtin_amdgcn_mfma_f32_16x16x32_f16(Af1, Bvk, AC1, 0, 0, 0); \
        AC2 = __builtin_amdgcn_mfma_f32_16x16x32_f16(Af2, Bvm, AC2, 0, 0, 0); }

        DO_TILE(rl0, tt0, ac0_0, ac1_0, ac2_0)
        DO_TILE(rl1, tt1, ac0_1, ac1_1, ac2_1)
        DO_TILE(rl2, tt2, ac0_2, ac1_2, ac2_2)
        DO_TILE(rl3, tt3, ac0_3, ac1_3, ac2_3)
#undef DO_TILE
#undef ARG2
    }

#define EPI(TC, AC0, AC1, AC2) { \
    long rowbase = (long)TC * NS + s0 + quad * 4; \
    _Pragma("unroll") \
    for (int rg = 0; rg < 4; ++rg) { \
        float vi = fminf(fmaxf(AC0[rg], 0.f), 1.f); \
        float vk = fminf(fmaxf(AC1[rg], 0.f), 1.f); \
        float vm = __builtin_amdgcn_exp2f(AC2[rg]); \
        unsigned pk = (unsigned)(vi * 65535.f + 0.5f) | ((unsigned)(vk * 65535.f + 0.5f) << 16); \
        VMK[(rowbase + rg) * NH + ml] = make_uint2(pk, __float_as_uint(vm)); \
    } }

    EPI(tc0, ac0_0, ac1_0, ac2_0)
    EPI(tc1, ac0_1, ac1_1, ac2_1)
    EPI(tc2, ac0_2, ac1_2, ac2_2)
    EPI(tc3, ac0_3, ac1_3, ac2_3)
#undef EPI

    {
        int tq = t0 + quad; if (tq >= NT) tq = NT - 1;
        const float* xq = X + ((long)tq * NS + srow) * 6;
        float2 peq = *(const float2*)xq;
        float2 ttq = *(const float2*)(xq + 2);
        store_pse(PSE, (long)tq * NS + srow, peq, ttq);
    }
}

// ---------------------------------------------------------------------------
// k_scan v4t: exact R6 structure (1 ch/lane, 14-deep rings, 4 basins/wave)
//   with ONE change: the 15-tap accumulation is re-associated into 4 parallel
//   sub-chains (depth <=4) + a 3-deep combine, cutting the y-path's dependent
//   FMA chain ~84 -> ~35 cyc/step. R4 measured the post-recurrence path is
//   timing-relevant (4 dependent shuffles cost ~100us over 730 steps).
//   FP re-association only; outputs f16-rounded -> absmax expected unchanged.
// ---------------------------------------------------------------------------
__global__ __launch_bounds__(64) void k_scan(
    const uint2* __restrict__ VMK, const float4* __restrict__ PSE,
    const float* __restrict__ P8, const float* __restrict__ RKGA,
    _Float16* __restrict__ YH)
{
    int lane = threadIdx.x;
    int s = blockIdx.x * 4 + (lane >> 4);
    int hh = lane & 15;
    size_t ch = (size_t)s * NH + hh;

    const float4* pp = (const float4*)(P8 + (size_t)ch * 8);
    float4 pa = pp[0], pb4 = pp[1];
    float k1 = pa.x, k2 = pa.y, k23 = pa.z, k3 = pa.w;
    float gl = pb4.x, qb = pb4.y, ge1 = pb4.z, ge2 = pb4.w;

    float rk[16];
    {
        const float4* rp = (const float4*)(RKGA + (size_t)ch * 16);
#pragma unroll
        for (int i = 0; i < 4; ++i) {
            float4 v = rp[i];
            rk[4 * i] = v.x; rk[4 * i + 1] = v.y; rk[4 * i + 2] = v.z; rk[4 * i + 3] = v.w;
        }
    }

    float S0 = 0.f, Sv = 0.f, S2 = 0.f, S3 = 0.f;
    float qr[14];
#pragma unroll
    for (int i = 0; i < 14; ++i) qr[i] = 0.f;

    uint2 vb[14]; float4 pbf[14];
#pragma unroll
    for (int i = 0; i < 14; ++i) {
        vb[i] = VMK[(size_t)i * NSNH + ch];
        pbf[i] = PSE[(size_t)i * NS + s];
    }

    int t = 0;
    // QD(d): tap d (d=1..14) = qr[(I+14-d)%14] * rk[d]
#define QD(I, d) (qr[((I) + 14 - (d)) % 14] * rk[d])
#define SBODY(I) { \
    uint2 v = vb[I]; float4 ps = pbf[I]; \
    int t2 = t + 14; if (t2 > NT - 1) t2 = NT - 1; \
    vb[I] = VMK[(size_t)t2 * NSNH + ch]; \
    pbf[I] = PSE[(size_t)t2 * NS + s]; \
    float vi = (float)(v.x & 0xffffu) * (1.f / 65535.f); \
    float vk = (float)(v.x >> 16) * (1.f / 65535.f); \
    float vm = __uint_as_float(v.y); \
    float Ps = ps.x, Pl = ps.y, E = ps.z; \
    float H0 = S0 + Ps; \
    float qSm = fminf(H0, vm); S0 = H0 - qSm; \
    float Hv = fmaxf(Sv + Pl * (1.f - vi) - E * ge1, 0.f); \
    float qv = Sv * vk; Sv = Hv - qv; \
    float H2 = fmaxf(S2 + qSm + qv - E * ge2 + Pl * vi, 0.f); \
    float x1 = H2 - gl; \
    float Q1 = (x1 > 0.f) ? __expf(k1 * __logf(x1)) : 0.f; \
    float q2 = fminf(H2, gl) * k2; \
    float Q2 = q2 * (1.f - k23); \
    float H3 = S3 + q2 * k23; \
    float Q3 = H3 * k3 + qb; \
    S2 = H2 - Q1 - q2; S3 = H3 - Q3; \
    float qt = Q1 + Q2 + Q3; \
    float g1 = QD(I, 1); \
    g1 = fmaf(qr[((I) + 12) % 14], rk[2],  g1); \
    g1 = fmaf(qr[((I) + 11) % 14], rk[3],  g1); \
    g1 = fmaf(qr[((I) + 10) % 14], rk[4],  g1); \
    float g2 = QD(I, 5); \
    g2 = fmaf(qr[((I) + 8)  % 14], rk[6],  g2); \
    g2 = fmaf(qr[((I) + 7)  % 14], rk[7],  g2); \
    g2 = fmaf(qr[((I) + 6)  % 14], rk[8],  g2); \
    float g3 = QD(I, 9); \
    g3 = fmaf(qr[((I) + 4)  % 14], rk[10], g3); \
    g3 = fmaf(qr[((I) + 3)  % 14], rk[11], g3); \
    float g4 = QD(I, 12); \
    g4 = fmaf(qr[((I) + 1)  % 14], rk[13], g4); \
    g4 = fmaf(qr[((I) + 0)  % 14], rk[14], g4); \
    float y = fmaf(qt, rk[0], (g1 + g2) + (g3 + g4)); \
    qr[I] = qt; \
    YH[(size_t)t * NSNH + ch] = (_Float16)y; \
    ++t; }

    for (int tb = 0; tb < 52; ++tb) {          // 52 * 14 = 728 steps
        SBODY(0) SBODY(1) SBODY(2) SBODY(3) SBODY(4) SBODY(5) SBODY(6)
        SBODY(7) SBODY(8) SBODY(9) SBODY(10) SBODY(11) SBODY(12) SBODY(13)
    }
    SBODY(0) SBODY(1)                          // steps 728, 729
#undef SBODY
#undef QD
}

// ---------------------------------------------------------------------------
// k_reduce: OUT[t,s] = sum_h YH[t, s*16+h]. One thread per (t,s); 32 B
//   contiguous per lane -> coalesced 2 KB per wave.
// ---------------------------------------------------------------------------
__global__ __launch_bounds__(256) void k_reduce(
    const _Float16* __restrict__ YH, float* __restrict__ OUT)
{
    long m = (long)blockIdx.x * 256 + threadIdx.x;
    if (m >= (long)NT * NS) return;
    int t = (int)(m / NS), s = (int)(m % NS);
    const _Float16* q = YH + (size_t)t * NSNH + (size_t)s * NH;
    f16x8 a = *(const f16x8*)q;
    f16x8 b = *(const f16x8*)(q + 8);
    float acc = 0.f;
#pragma unroll
    for (int i = 0; i < 8; ++i) acc += (float)a[i];
#pragma unroll
    for (int i = 0; i < 8; ++i) acc += (float)b[i];
    OUT[m] = acc;
}

// ---------------------------------------------------------------------------
extern "C" void kernel_launch(void* const* d_in, const int* in_sizes, int n_in,
                              void* d_out, int out_size, void* d_ws, size_t ws_size,
                              hipStream_t stream)
{
    const float* X    = (const float*)d_in[0];
    const float* XC   = (const float*)d_in[1];
    const float* fcW1 = (const float*)d_in[2];
    const float* fcb1 = (const float*)d_in[3];
    const float* fcW2 = (const float*)d_in[4];
    const float* fcb2 = (const float*)d_in[5];
    const float* fRW1 = (const float*)d_in[6];
    const float* fRb1 = (const float*)d_in[7];
    const float* fRW2 = (const float*)d_in[8];
    const float* fRb2 = (const float*)d_in[9];
    const float* T1W1 = (const float*)d_in[10];
    const float* T1b1 = (const float*)d_in[11];
    const float* T1W2 = (const float*)d_in[12];
    const float* T1b2 = (const float*)d_in[13];
    const float* T2W1 = (const float*)d_in[14];
    const float* T2b1 = (const float*)d_in[15];
    const float* T2W2 = (const float*)d_in[16];
    const float* T2b2 = (const float*)d_in[17];
    float* OUT = (float*)d_out;

    char* w = (char*)d_ws;
    uint2* VMK     = (uint2*)w;     w += (size_t)NT * NSNH * 8;     // 186.9 MB
    float4* PSE    = (float4*)w;    w += (size_t)NT * NS * 16;      // 23.4 MB
    _Float16* YH   = (_Float16*)w;  w += (size_t)NT * NSNH * 2;     // 46.7 MB
    float2* BASE12 = (float2*)w;    w += (size_t)NS * HID * 8;      // 4.1 MB
    float* P8      = (float*)w;     w += (size_t)NS * NH * 8 * 4;
    float* RKGA    = (float*)w;     w += (size_t)NS * NH * 16 * 4;
    _Float16* W2H  = (_Float16*)w;  w += 48 * HID * 2;
    float4* CC4    = (float4*)w;    w += HID * 16;
    float* BIAS48  = (float*)w;     w += 64 * 4;
    (void)ws_size; (void)in_sizes; (void)n_in; (void)out_size;

    k_pack<<<dim3(1), dim3(256), 0, stream>>>(T1W1, T2W1, T1W2, T2W2, T1b2, T2b2,
                                              CC4, W2H, BIAS48);
    k_basin<<<dim3(NS / 4), dim3(256), 0, stream>>>(XC, fcW1, fcb1, fcW2, fcb2,
                                                    fRW1, fRb1, fRW2, fRb2,
                                                    T1W1, T1b1, T2W1, T2b1,
                                                    P8, RKGA, BASE12);
    // grid: s-tiles fastest (x=125, write locality); y = 8-t slab via 2 waves
    // (92 * 2 * 4 = 736 >= 730).
    k_mlp<<<dim3(125, 92), dim3(128), 0, stream>>>(
        X, BASE12, CC4, W2H, BIAS48, VMK, PSE);
    k_scan<<<dim3(NS / 4), dim3(64), 0, stream>>>(VMK, PSE, P8, RKGA, YH);
    k_reduce<<<dim3((unsigned)(((long)NT * NS + 255) / 256)), dim3(256), 0, stream>>>(YH, OUT);
}

// Round 10
// 508.336 us; speedup vs baseline: 1.1794x; 1.0642x over previous
//
#include <hip/hip_runtime.h>
#include <math.h>

#define NT 730
#define NS 2000
#define NH 16
#define NG 32
#define NR 15
#define HID 256
#define NSNH 32000

// 2*log2(e): pre-folded into BASE12/CC4 so the hidden-layer arg is a bare fma.
// tanh(x) = 1 - 2*r, r = rcp(exp2(SC*x)+1). The (1-2r) affine is folded into
// the MFMA weights (W2H = -2*w_f16) and the accumulator init
// (BIAS48 = b + sum_k w_f16), so only r is fed to the matrix core.
#define SC 2.885390081777927f
#define INV6 0.16666666666666666f

typedef _Float16 f16x8 __attribute__((ext_vector_type(8)));
typedef __fp16 fp16v2 __attribute__((ext_vector_type(2)));   // cvt_pkrtz native return type
typedef float f32x4 __attribute__((ext_vector_type(4)));

__device__ __forceinline__ float tanh_pre(float y) {   // y = SC * x
    float e = __builtin_amdgcn_exp2f(y);
    float r = __builtin_amdgcn_rcpf(e + 1.f);
    return fmaf(-2.f, r, 1.f);
}
__device__ __forceinline__ float fast_tanh(float x) { return tanh_pre(x * SC); }
__device__ __forceinline__ float sigmoidf_(float x) { return 1.f / (1.f + __expf(-x)); }

__device__ __forceinline__ float rcp_pre(float y) {    // r = 1/(1+exp2(y)); tanh = 1-2r
    float e = __builtin_amdgcn_exp2f(y);
    return __builtin_amdgcn_rcpf(e + 1.f);
}
__device__ __forceinline__ f16x8 rcp8(float4 lo, float4 hi) {
    union { fp16v2 h[4]; f16x8 v; } u;
    u.h[0] = __builtin_amdgcn_cvt_pkrtz(rcp_pre(lo.x), rcp_pre(lo.y));
    u.h[1] = __builtin_amdgcn_cvt_pkrtz(rcp_pre(lo.z), rcp_pre(lo.w));
    u.h[2] = __builtin_amdgcn_cvt_pkrtz(rcp_pre(hi.x), rcp_pre(hi.y));
    u.h[3] = __builtin_amdgcn_cvt_pkrtz(rcp_pre(hi.z), rcp_pre(hi.w));
    return u.v;
}

// ---------------------------------------------------------------------------
// k_basin (+ fused k_pack): blocks 0..499 do the per-basin MLPs; block 500
//   does the former k_pack work (CC4/W2H/BIAS48). Both precede k_mlp, so
//   fusing removes one serialized 1-block dispatch. Outputs byte-identical.
// ---------------------------------------------------------------------------
__global__ __launch_bounds__(256) void k_basin(
    const float* __restrict__ XC,
    const float* __restrict__ fcW1, const float* __restrict__ fcb1,
    const float* __restrict__ fcW2, const float* __restrict__ fcb2,
    const float* __restrict__ fRW1, const float* __restrict__ fRb1,
    const float* __restrict__ fRW2, const float* __restrict__ fRb2,
    const float* __restrict__ T1W1, const float* __restrict__ T1b1,
    const float* __restrict__ T2W1, const float* __restrict__ T2b1,
    const float* __restrict__ T1W2, const float* __restrict__ T1b2,
    const float* __restrict__ T2W2, const float* __restrict__ T2b2,
    float* __restrict__ P8, float* __restrict__ RKGA,
    float2* __restrict__ BASE12,
    float4* __restrict__ CC4, _Float16* __restrict__ W2H,
    float* __restrict__ BIAS48)
{
    const int tid = threadIdx.x;

    if (blockIdx.x == NS / 4) {                 // fused k_pack (1 block)
        int k = tid;
        CC4[k] = make_float4(SC * T1W1[k * (1 + NG)],
                             SC * T2W1[k * (3 + NG)],
                             SC * T2W1[k * (3 + NG) + 1],
                             SC * T2W1[k * (3 + NG) + 2]);
        for (int c = 0; c < 48; ++c) {
            float w = (c < 32) ? (INV6 * T1W2[c * HID + k]) : (SC * T2W2[(c - 32) * HID + k]);
            W2H[c * HID + k] = (_Float16)(-2.f * w);
        }
        if (k < 48) {
            float s = 0.f;
            if (k < 32) {
                for (int i = 0; i < HID; ++i)
                    s += -0.5f * (float)(_Float16)(-2.f * INV6 * T1W2[k * HID + i]);
                BIAS48[k] = fmaf(T1b2[k], INV6, 0.5f) + s;
            } else {
                for (int i = 0; i < HID; ++i)
                    s += -0.5f * (float)(_Float16)(-2.f * SC * T2W2[(k - 32) * HID + i]);
                BIAS48[k] = SC * T2b2[k - 32] + s;
            }
        }
        return;
    }

    const int s0 = blockIdx.x * 4;
    __shared__ float xcs[4][NG];
    __shared__ float h[4][HID], hR[4][HID];
    __shared__ float wbuf[4][10 * NH], wRbuf[4][NH * NR];
    __shared__ float gav[4][NH];

    if (tid < 128) xcs[tid >> 5][tid & 31] = XC[(s0 + (tid >> 5)) * NG + (tid & 31)];
    __syncthreads();

    {
        float ab0 = fcb1[tid], ab1 = ab0, ab2 = ab0, ab3 = ab0;
        float rb0 = fRb1[tid], rb1 = rb0, rb2 = rb0, rb3 = rb0;
        const float4* w4  = (const float4*)(fcW1 + tid * NG);
        const float4* wR4 = (const float4*)(fRW1 + tid * NG);
#pragma unroll
        for (int g = 0; g < NG / 4; ++g) {
            float4 wv = w4[g], rv = wR4[g];
            float4 x0 = *(const float4*)&xcs[0][g * 4];
            float4 x1 = *(const float4*)&xcs[1][g * 4];
            float4 x2 = *(const float4*)&xcs[2][g * 4];
            float4 x3 = *(const float4*)&xcs[3][g * 4];
            ab0 += x0.x*wv.x + x0.y*wv.y + x0.z*wv.z + x0.w*wv.w;
            ab1 += x1.x*wv.x + x1.y*wv.y + x1.z*wv.z + x1.w*wv.w;
            ab2 += x2.x*wv.x + x2.y*wv.y + x2.z*wv.z + x2.w*wv.w;
            ab3 += x3.x*wv.x + x3.y*wv.y + x3.z*wv.z + x3.w*wv.w;
            rb0 += x0.x*rv.x + x0.y*rv.y + x0.z*rv.z + x0.w*rv.w;
            rb1 += x1.x*rv.x + x1.y*rv.y + x1.z*rv.z + x1.w*rv.w;
            rb2 += x2.x*rv.x + x2.y*rv.y + x2.z*rv.z + x2.w*rv.w;
            rb3 += x3.x*rv.x + x3.y*rv.y + x3.z*rv.z + x3.w*rv.w;
        }
        h[0][tid] = fast_tanh(ab0); h[1][tid] = fast_tanh(ab1);
        h[2][tid] = fast_tanh(ab2); h[3][tid] = fast_tanh(ab3);
        hR[0][tid] = fast_tanh(rb0); hR[1][tid] = fast_tanh(rb1);
        hR[2][tid] = fast_tanh(rb2); hR[3][tid] = fast_tanh(rb3);

        float b10 = T1b1[tid], b11 = b10, b12 = b10, b13 = b10;
        float b20 = T2b1[tid], b21 = b20, b22 = b20, b23 = b20;
        const float* w1 = T1W1 + tid * (1 + NG) + 1;
        const float* w2 = T2W1 + tid * (3 + NG) + 3;
#pragma unroll 8
        for (int g = 0; g < NG; ++g) {
            float w1g = w1[g], w2g = w2[g];
            float x0 = xcs[0][g], x1 = xcs[1][g], x2 = xcs[2][g], x3 = xcs[3][g];
            b10 = fmaf(x0, w1g, b10); b11 = fmaf(x1, w1g, b11);
            b12 = fmaf(x2, w1g, b12); b13 = fmaf(x3, w1g, b13);
            b20 = fmaf(x0, w2g, b20); b21 = fmaf(x1, w2g, b21);
            b22 = fmaf(x2, w2g, b22); b23 = fmaf(x3, w2g, b23);
        }
        BASE12[(size_t)(s0 + 0) * HID + tid] = make_float2(SC * b10, SC * b20);
        BASE12[(size_t)(s0 + 1) * HID + tid] = make_float2(SC * b11, SC * b21);
        BASE12[(size_t)(s0 + 2) * HID + tid] = make_float2(SC * b12, SC * b22);
        BASE12[(size_t)(s0 + 3) * HID + tid] = make_float2(SC * b13, SC * b23);
    }
    __syncthreads();

    if (tid < 10 * NH) {
        float a0 = fcb2[tid], a1 = a0, a2 = a0, a3 = a0;
        const float4* w4 = (const float4*)(fcW2 + tid * HID);
        for (int k = 0; k < HID / 4; ++k) {
            float4 wv = w4[k];
            float4 h0 = *(const float4*)&h[0][k * 4];
            float4 h1 = *(const float4*)&h[1][k * 4];
            float4 h2 = *(const float4*)&h[2][k * 4];
            float4 h3 = *(const float4*)&h[3][k * 4];
            a0 += h0.x*wv.x + h0.y*wv.y + h0.z*wv.z + h0.w*wv.w;
            a1 += h1.x*wv.x + h1.y*wv.y + h1.z*wv.z + h1.w*wv.w;
            a2 += h2.x*wv.x + h2.y*wv.y + h2.z*wv.z + h2.w*wv.w;
            a3 += h3.x*wv.x + h3.y*wv.y + h3.z*wv.z + h3.w*wv.w;
        }
        wbuf[0][tid] = a0; wbuf[1][tid] = a1; wbuf[2][tid] = a2; wbuf[3][tid] = a3;
    }
    if (tid < NH * NR) {
        float a0 = fRb2[tid], a1 = a0, a2 = a0, a3 = a0;
        const float4* w4 = (const float4*)(fRW2 + tid * HID);
        for (int k = 0; k < HID / 4; ++k) {
            float4 wv = w4[k];
            float4 h0 = *(const float4*)&hR[0][k * 4];
            float4 h1 = *(const float4*)&hR[1][k * 4];
            float4 h2 = *(const float4*)&hR[2][k * 4];
            float4 h3 = *(const float4*)&hR[3][k * 4];
            a0 += h0.x*wv.x + h0.y*wv.y + h0.z*wv.z + h0.w*wv.w;
            a1 += h1.x*wv.x + h1.y*wv.y + h1.z*wv.z + h1.w*wv.w;
            a2 += h2.x*wv.x + h2.y*wv.y + h2.z*wv.z + h2.w*wv.w;
            a3 += h3.x*wv.x + h3.y*wv.y + h3.z*wv.z + h3.w*wv.w;
        }
        wRbuf[0][tid] = a0; wRbuf[1][tid] = a1; wRbuf[2][tid] = a2; wRbuf[3][tid] = a3;
    }
    __syncthreads();

    if (tid < 64) {
        int b = tid >> 4, hh = tid & 15;
        const float* wb = wbuf[b];
        float mx = -1e30f;
        for (int i = 0; i < NH; ++i) mx = fmaxf(mx, wb[6 * NH + i]);
        float sum = 0.f;
        for (int i = 0; i < NH; ++i) sum += expf(wb[6 * NH + i] - mx);
        gav[b][hh] = expf(wb[6 * NH + hh] - mx) / sum;

        float* p = P8 + (size_t)((s0 + b) * NH + hh) * 8;
        p[0] = sigmoidf_(wb[1 * NH + hh]);
        p[1] = sigmoidf_(wb[2 * NH + hh]);
        p[2] = sigmoidf_(wb[3 * NH + hh]);
        p[3] = sigmoidf_(wb[4 * NH + hh]) * 0.1f;
        p[4] = expf(wb[5 * NH + hh]) * 2.f;
        p[5] = fmaxf(wb[7 * NH + hh], 0.f);
        p[6] = fmaxf(wb[8 * NH + hh], 0.f);
        p[7] = fmaxf(wb[9 * NH + hh], 0.f);
    }
    __syncthreads();

    for (int it = tid; it < 4 * NH * NR; it += 256) {
        int b = it / (NH * NR), r = it % (NH * NR);
        int hh = r / NR, j = r % NR;
        RKGA[(size_t)((s0 + b) * NH + hh) * 16 + (NR - 1 - j)] =
            gav[b][hh] * fmaxf(wRbuf[b][hh * NR + j], 0.f);
    }
}

// ---------------------------------------------------------------------------
// PSE helper (vp partition).
// ---------------------------------------------------------------------------
__device__ __forceinline__ void store_pse(float4* __restrict__ PSE, long m, float2 pe, float2 t12) {
    float P = pe.x, E = pe.y, T1 = t12.x, T2 = t12.y;
    float den = T2 - T1;
    float ratio = (T1 + T2) / ((den == 0.f) ? 1.f : den);
    ratio = fminf(fmaxf(ratio, -1.f), 1.f);
    if ((T1 >= 0.f) || (T2 <= 0.f)) ratio = 0.f;
    float vp = 1.f - acosf(ratio) * (1.f / 3.1415f);
    if (T1 >= 0.f) vp = 1.f;
    if (T2 <= 0.f) vp = 0.f;
    PSE[m] = make_float4(P * (1.f - vp), P * vp, E, 0.f);
}

// ---------------------------------------------------------------------------
// k_mlp v10 (unchanged, R6 best): 2-wave/128-thread blocks, rcp fold,
//   s-fastest grid. ~255us, VGPR 88, WRITE 205MB clean.
// ---------------------------------------------------------------------------
__global__ __launch_bounds__(128) void k_mlp(
    const float* __restrict__ X,
    const float2* __restrict__ BASE12, const float4* __restrict__ CC4,
    const _Float16* __restrict__ W2H, const float* __restrict__ BIAS48,
    uint2* __restrict__ VMK, float4* __restrict__ PSE)
{
    const int lane = threadIdx.x & 63;
    const int wave = threadIdx.x >> 6;
    const int quad = lane >> 4, ml = lane & 15;
    const int s0 = blockIdx.x * 16;
    const int t0 = (blockIdx.y * 2 + wave) * 4;
    const int srow = s0 + ml;

    const int tc0 = (t0 < NT) ? t0 : (NT - 1);
    const int tc1 = (t0 + 1 < NT) ? t0 + 1 : (NT - 1);
    const int tc2 = (t0 + 2 < NT) ? t0 + 2 : (NT - 1);
    const int tc3 = (t0 + 3 < NT) ? t0 + 3 : (NT - 1);

    const float* xr0 = X + ((long)tc0 * NS + srow) * 6;
    const float* xr1 = X + ((long)tc1 * NS + srow) * 6;
    const float* xr2 = X + ((long)tc2 * NS + srow) * 6;
    const float* xr3 = X + ((long)tc3 * NS + srow) * 6;
    float2 tt0 = *(const float2*)(xr0 + 2), rl0 = *(const float2*)(xr0 + 4);
    float2 tt1 = *(const float2*)(xr1 + 2), rl1 = *(const float2*)(xr1 + 4);
    float2 tt2 = *(const float2*)(xr2 + 2), rl2 = *(const float2*)(xr2 + 4);
    float2 tt3 = *(const float2*)(xr3 + 2), rl3 = *(const float2*)(xr3 + 4);

    const float bvi = BIAS48[ml];
    const float bvk = BIAS48[NH + ml];
    const float bvm = BIAS48[2 * NH + ml];
    f32x4 ac0_0 = {bvi, bvi, bvi, bvi}, ac0_1 = ac0_0, ac0_2 = ac0_0, ac0_3 = ac0_0;
    f32x4 ac1_0 = {bvk, bvk, bvk, bvk}, ac1_1 = ac1_0, ac1_2 = ac1_0, ac1_3 = ac1_0;
    f32x4 ac2_0 = {bvm, bvm, bvm, bvm}, ac2_1 = ac2_0, ac2_2 = ac2_0, ac2_3 = ac2_0;

    const float2* b12p = BASE12 + (size_t)srow * HID;
    const _Float16* wvi = W2H + (size_t)ml * HID;
    const _Float16* wvk = W2H + (size_t)(NH + ml) * HID;
    const _Float16* wvm = W2H + (size_t)(2 * NH + ml) * HID;

#pragma unroll 2
    for (int ks = 0; ks < 8; ++ks) {
        const int kb = ks * 32 + quad * 8;
        float4 cc0 = CC4[kb], cc1 = CC4[kb + 1], cc2 = CC4[kb + 2], cc3 = CC4[kb + 3];
        float4 cc4 = CC4[kb + 4], cc5 = CC4[kb + 5], cc6 = CC4[kb + 6], cc7 = CC4[kb + 7];
        float4 bA = *(const float4*)(b12p + kb);       // b1[k],b2[k],b1[k+1],b2[k+1]
        float4 bB = *(const float4*)(b12p + kb + 2);
        float4 bC = *(const float4*)(b12p + kb + 4);
        float4 bD = *(const float4*)(b12p + kb + 6);
        f16x8 Bvi = *(const f16x8*)(wvi + kb);
        f16x8 Bvk = *(const f16x8*)(wvk + kb);
        f16x8 Bvm = *(const f16x8*)(wvm + kb);

#define ARG2(CC, B2, TT, RL) fmaf(TT.y, CC.w, fmaf(TT.x, CC.z, fmaf(RL.x, CC.y, B2)))
#define DO_TILE(RL, TT, AC0, AC1, AC2) { \
        float4 a1lo = make_float4(fmaf(RL.y, cc0.x, bA.x), fmaf(RL.y, cc1.x, bA.z), \
                                  fmaf(RL.y, cc2.x, bB.x), fmaf(RL.y, cc3.x, bB.z)); \
        float4 a1hi = make_float4(fmaf(RL.y, cc4.x, bC.x), fmaf(RL.y, cc5.x, bC.z), \
                                  fmaf(RL.y, cc6.x, bD.x), fmaf(RL.y, cc7.x, bD.z)); \
        f16x8 Af1 = rcp8(a1lo, a1hi); \
        float4 a2lo = make_float4(ARG2(cc0, bA.y, TT, RL), ARG2(cc1, bA.w, TT, RL), \
                                  ARG2(cc2, bB.y, TT, RL), ARG2(cc3, bB.w, TT, RL)); \
        float4 a2hi = make_float4(ARG2(cc4, bC.y, TT, RL), ARG2(cc5, bC.w, TT, RL), \
                                  ARG2(cc6, bD.y, TT, RL), ARG2(cc7, bD.w, TT, RL)); \
        f16x8 Af2 = rcp8(a2lo, a2hi); \
        AC0 = __builtin_amdgcn_mfma_f32_16x16x32_f16(Af1, Bvi, AC0, 0, 0, 0); \
        AC1 = __builtin_amdgcn_mfma_f32_16x16x32_f16(Af1, Bvk, AC1, 0, 0, 0); \
        AC2 = __builtin_amdgcn_mfma_f32_16x16x32_f16(Af2, Bvm, AC2, 0, 0, 0); }

        DO_TILE(rl0, tt0, ac0_0, ac1_0, ac2_0)
        DO_TILE(rl1, tt1, ac0_1, ac1_1, ac2_1)
        DO_TILE(rl2, tt2, ac0_2, ac1_2, ac2_2)
        DO_TILE(rl3, tt3, ac0_3, ac1_3, ac2_3)
#undef DO_TILE
#undef ARG2
    }

#define EPI(TC, AC0, AC1, AC2) { \
    long rowbase = (long)TC * NS + s0 + quad * 4; \
    _Pragma("unroll") \
    for (int rg = 0; rg < 4; ++rg) { \
        float vi = fminf(fmaxf(AC0[rg], 0.f), 1.f); \
        float vk = fminf(fmaxf(AC1[rg], 0.f), 1.f); \
        float vm = __builtin_amdgcn_exp2f(AC2[rg]); \
        unsigned pk = (unsigned)(vi * 65535.f + 0.5f) | ((unsigned)(vk * 65535.f + 0.5f) << 16); \
        VMK[(rowbase + rg) * NH + ml] = make_uint2(pk, __float_as_uint(vm)); \
    } }

    EPI(tc0, ac0_0, ac1_0, ac2_0)
    EPI(tc1, ac0_1, ac1_1, ac2_1)
    EPI(tc2, ac0_2, ac1_2, ac2_2)
    EPI(tc3, ac0_3, ac1_3, ac2_3)
#undef EPI

    {
        int tq = t0 + quad; if (tq >= NT) tq = NT - 1;
        const float* xq = X + ((long)tq * NS + srow) * 6;
        float2 peq = *(const float2*)xq;
        float2 ttq = *(const float2*)(xq + 2);
        store_pse(PSE, (long)tq * NS + srow, peq, ttq);
    }
}

// ---------------------------------------------------------------------------
// k_scan v4 (R6 best, unchanged): recurrence + in-register 15-tap conv per
//   channel (mod-14 ring, constant indices). Stores per-channel conv output
//   YH[t,ch] (fp16); h-reduction deferred to k_reduce. Survived 4 structural
//   attack angles (fused reduce +75us, 28-ring +62us, 2ch/lane +39us,
//   tap-tree ~0) — keep as-is.
// ---------------------------------------------------------------------------
__global__ __launch_bounds__(64) void k_scan(
    const uint2* __restrict__ VMK, const float4* __restrict__ PSE,
    const float* __restrict__ P8, const float* __restrict__ RKGA,
    _Float16* __restrict__ YH)
{
    int lane = threadIdx.x;
    int s = blockIdx.x * 4 + (lane >> 4);
    int hh = lane & 15;
    size_t ch = (size_t)s * NH + hh;

    const float4* pp = (const float4*)(P8 + (size_t)ch * 8);
    float4 pa = pp[0], pb4 = pp[1];
    float k1 = pa.x, k2 = pa.y, k23 = pa.z, k3 = pa.w;
    float gl = pb4.x, qb = pb4.y, ge1 = pb4.z, ge2 = pb4.w;

    float rk[16];
    {
        const float4* rp = (const float4*)(RKGA + (size_t)ch * 16);
#pragma unroll
        for (int i = 0; i < 4; ++i) {
            float4 v = rp[i];
            rk[4 * i] = v.x; rk[4 * i + 1] = v.y; rk[4 * i + 2] = v.z; rk[4 * i + 3] = v.w;
        }
    }

    float S0 = 0.f, Sv = 0.f, S2 = 0.f, S3 = 0.f;
    float qr[14];
#pragma unroll
    for (int i = 0; i < 14; ++i) qr[i] = 0.f;

    uint2 vb[14]; float4 pbf[14];
#pragma unroll
    for (int i = 0; i < 14; ++i) {
        vb[i] = VMK[(size_t)i * NSNH + ch];
        pbf[i] = PSE[(size_t)i * NS + s];
    }

    int t = 0;
#define SBODY(I) { \
    uint2 v = vb[I]; float4 ps = pbf[I]; \
    int t2 = t + 14; if (t2 > NT - 1) t2 = NT - 1; \
    vb[I] = VMK[(size_t)t2 * NSNH + ch]; \
    pbf[I] = PSE[(size_t)t2 * NS + s]; \
    float vi = (float)(v.x & 0xffffu) * (1.f / 65535.f); \
    float vk = (float)(v.x >> 16) * (1.f / 65535.f); \
    float vm = __uint_as_float(v.y); \
    float Ps = ps.x, Pl = ps.y, E = ps.z; \
    float H0 = S0 + Ps; \
    float qSm = fminf(H0, vm); S0 = H0 - qSm; \
    float Hv = fmaxf(Sv + Pl * (1.f - vi) - E * ge1, 0.f); \
    float qv = Sv * vk; Sv = Hv - qv; \
    float H2 = fmaxf(S2 + qSm + qv - E * ge2 + Pl * vi, 0.f); \
    float x1 = H2 - gl; \
    float Q1 = (x1 > 0.f) ? __expf(k1 * __logf(x1)) : 0.f; \
    float q2 = fminf(H2, gl) * k2; \
    float Q2 = q2 * (1.f - k23); \
    float H3 = S3 + q2 * k23; \
    float Q3 = H3 * k3 + qb; \
    S2 = H2 - Q1 - q2; S3 = H3 - Q3; \
    float qt = Q1 + Q2 + Q3; \
    float y = qt * rk[0]; \
    _Pragma("unroll") for (int d = 1; d <= 14; ++d) y += qr[((I) + 14 - d) % 14] * rk[d]; \
    qr[I] = qt; \
    YH[(size_t)t * NSNH + ch] = (_Float16)y; \
    ++t; }

    for (int tb = 0; tb < 52; ++tb) {          // 52 * 14 = 728 steps
        SBODY(0) SBODY(1) SBODY(2) SBODY(3) SBODY(4) SBODY(5) SBODY(6)
        SBODY(7) SBODY(8) SBODY(9) SBODY(10) SBODY(11) SBODY(12) SBODY(13)
    }
    SBODY(0) SBODY(1)                          // steps 728, 729
#undef SBODY
}

// ---------------------------------------------------------------------------
// k_reduce: OUT[t,s] = sum_h YH[t, s*16+h]. One thread per (t,s); 32 B
//   contiguous per lane -> coalesced 2 KB per wave.
// ---------------------------------------------------------------------------
__global__ __launch_bounds__(256) void k_reduce(
    const _Float16* __restrict__ YH, float* __restrict__ OUT)
{
    long m = (long)blockIdx.x * 256 + threadIdx.x;
    if (m >= (long)NT * NS) return;
    int t = (int)(m / NS), s = (int)(m % NS);
    const _Float16* q = YH + (size_t)t * NSNH + (size_t)s * NH;
    f16x8 a = *(const f16x8*)q;
    f16x8 b = *(const f16x8*)(q + 8);
    float acc = 0.f;
#pragma unroll
    for (int i = 0; i < 8; ++i) acc += (float)a[i];
#pragma unroll
    for (int i = 0; i < 8; ++i) acc += (float)b[i];
    OUT[m] = acc;
}

// ---------------------------------------------------------------------------
extern "C" void kernel_launch(void* const* d_in, const int* in_sizes, int n_in,
                              void* d_out, int out_size, void* d_ws, size_t ws_size,
                              hipStream_t stream)
{
    const float* X    = (const float*)d_in[0];
    const float* XC   = (const float*)d_in[1];
    const float* fcW1 = (const float*)d_in[2];
    const float* fcb1 = (const float*)d_in[3];
    const float* fcW2 = (const float*)d_in[4];
    const float* fcb2 = (const float*)d_in[5];
    const float* fRW1 = (const float*)d_in[6];
    const float* fRb1 = (const float*)d_in[7];
    const float* fRW2 = (const float*)d_in[8];
    const float* fRb2 = (const float*)d_in[9];
    const float* T1W1 = (const float*)d_in[10];
    const float* T1b1 = (const float*)d_in[11];
    const float* T1W2 = (const float*)d_in[12];
    const float* T1b2 = (const float*)d_in[13];
    const float* T2W1 = (const float*)d_in[14];
    const float* T2b1 = (const float*)d_in[15];
    const float* T2W2 = (const float*)d_in[16];
    const float* T2b2 = (const float*)d_in[17];
    float* OUT = (float*)d_out;

    char* w = (char*)d_ws;
    uint2* VMK     = (uint2*)w;     w += (size_t)NT * NSNH * 8;     // 186.9 MB
    float4* PSE    = (float4*)w;    w += (size_t)NT * NS * 16;      // 23.4 MB
    _Float16* YH   = (_Float16*)w;  w += (size_t)NT * NSNH * 2;     // 46.7 MB
    float2* BASE12 = (float2*)w;    w += (size_t)NS * HID * 8;      // 4.1 MB
    float* P8      = (float*)w;     w += (size_t)NS * NH * 8 * 4;
    float* RKGA    = (float*)w;     w += (size_t)NS * NH * 16 * 4;
    _Float16* W2H  = (_Float16*)w;  w += 48 * HID * 2;
    float4* CC4    = (float4*)w;    w += HID * 16;
    float* BIAS48  = (float*)w;     w += 64 * 4;
    (void)ws_size; (void)in_sizes; (void)n_in; (void)out_size;

    // k_pack fused into k_basin as block NS/4 (grid 501).
    k_basin<<<dim3(NS / 4 + 1), dim3(256), 0, stream>>>(
        XC, fcW1, fcb1, fcW2, fcb2, fRW1, fRb1, fRW2, fRb2,
        T1W1, T1b1, T2W1, T2b1, T1W2, T1b2, T2W2, T2b2,
        P8, RKGA, BASE12, CC4, W2H, BIAS48);
    // grid: s-tiles fastest (x=125, write locality); y = 8-t slab via 2 waves
    // (92 * 2 * 4 = 736 >= 730).
    k_mlp<<<dim3(125, 92), dim3(128), 0, stream>>>(
        X, BASE12, CC4, W2H, BIAS48, VMK, PSE);
    k_scan<<<dim3(NS / 4), dim3(64), 0, stream>>>(VMK, PSE, P8, RKGA, YH);
    k_reduce<<<dim3((unsigned)(((long)NT * NS + 255) / 256)), dim3(256), 0, stream>>>(YH, OUT);
}